// Round 15
// baseline (443.550 us; speedup 1.0000x reference)
//
#include <hip/hip_runtime.h>
#include <math.h>

#define NN 65536   // nodes
#define NE 524288  // edges
#define NG 2048    // graphs
#define HD 256     // hidden
#define NL 50      // noise levels
#define CAP 64     // bucket capacity per node (Poisson(8): P(deg>64) ~ 1e-38)
#define BCAP 2560  // bin capacity (Poisson(2048), +11 sigma)

typedef unsigned short u16;
typedef unsigned char u8;
typedef __attribute__((ext_vector_type(8))) short short8;
typedef __attribute__((ext_vector_type(4))) float f32x4;
typedef __attribute__((ext_vector_type(4))) unsigned short us4;

__device__ __forceinline__ float bf2f(u16 h){
  union{unsigned int u; float f;} v; v.u = ((unsigned int)h)<<16; return v.f;
}
__device__ __forceinline__ u16 f2bf(float f){
  union{float f; unsigned int u;} v; v.f=f;
  return (u16)((v.u + 0x7FFFu + ((v.u>>16)&1u))>>16);
}
__device__ __forceinline__ float silu_f(float v){ return v/(1.0f+__expf(-v)); }
__device__ __forceinline__ u8 f2e4m3(float v){
  return (u8)__builtin_amdgcn_cvt_pk_fp8_f32(v, v, 0, false);
}
__device__ __forceinline__ float4 e4m3x4(unsigned w){
  float4 r;
  r.x = __builtin_amdgcn_cvt_f32_fp8(w, 0);
  r.y = __builtin_amdgcn_cvt_f32_fp8(w, 1);
  r.z = __builtin_amdgcn_cvt_f32_fp8(w, 2);
  r.w = __builtin_amdgcn_cvt_f32_fp8(w, 3);
  return r;
}

#define WRED(v) { v += __shfl_xor(v,1); v += __shfl_xor(v,2); v += __shfl_xor(v,4); \
                  v += __shfl_xor(v,8); v += __shfl_xor(v,16); v += __shfl_xor(v,32); }

// =========== k_pre: wmg (block 0) | graph boundaries (blocks 1..257) ===========
__global__ void k_pre(const float* __restrict__ Wm, const float* __restrict__ wgate,
                      const int* __restrict__ n2g,
                      float* __restrict__ wmg, int* __restrict__ gstart){
  int b = blockIdx.x, t = threadIdx.x;
  if(b==0){
    float s=0.f;
    for(int j=0;j<256;j++) s += Wm[t*256+j]*wgate[j];
    wmg[t]=s;
  } else {
    int i = (b-1)*256 + t;
    if(i>NN) return;
    int cur  = (i<NN)? n2g[i] : NG;
    int prev = (i==0)? -1 : n2g[i-1];
    for(int g=prev+1; g<=cur; ++g) gstart[g]=i;
  }
}

// =========== k_front3: wall | prep8(2 rows/wave) | radix-pass1 | kab ===========
// blocks: [0,1344) wall | [1344,9536) prep8 | [9536,11584) pass1 |
//         [11584,12096) kab (4 graphs/block)
__global__ __launch_bounds__(256) void k_front3(
        const float* __restrict__ x, const int* __restrict__ ei,
        const float* __restrict__ Wn, const float* __restrict__ Wm,
        const float* __restrict__ Wd1, const float* __restrict__ Wd2,
        const float* __restrict__ Wp1, const float* __restrict__ Wp2,
        const float* __restrict__ pos, const float* __restrict__ noise,
        const int* __restrict__ gstart, const int* __restrict__ nl,
        const float* __restrict__ wmg,
        u8* __restrict__ wn8, u8* __restrict__ wm8, u8* __restrict__ wd18,
        u16* __restrict__ wd2b, u16* __restrict__ wpeb, u16* __restrict__ wp2b,
        u8* __restrict__ xb8, float* __restrict__ cf,
        int* __restrict__ bincur, unsigned* __restrict__ pairs,
        float* __restrict__ sigg, float* __restrict__ posp,
        float* __restrict__ target){
  int b = blockIdx.x, t = threadIdx.x;
  if(b < 1344){
    if(b < 768){
      int m = b>>8;
      int idx = (b&255)*256 + t;
      int k = idx>>8, n = idx&255;
      const float* W = (m==0)? Wn : (m==1)? Wm : Wd1;
      u8* O = (m==0)? wn8 : (m==1)? wm8 : wd18;
      unsigned a = (unsigned)(n*256+k);
      O[a ^ ((unsigned)(n&15)<<3)] = f2e4m3(W[k*256+n]);   // pre-swizzled
    } else if(b < 1024){
      int idx = (b-768)*256 + t; int k=idx>>8, n=idx&255;
      wd2b[n*256+k] = f2bf(Wd2[k*256+n]);
    } else if(b < 1280){
      int idx = (b-1024)*256 + t; int k=idx>>8, n=idx&255;
      wpeb[n*256+k] = f2bf(Wp1[k*256+n] + Wp1[(k+256)*256+n]);
    } else {
      int idx = (b-1280)*256 + t; int k=idx&255, n=idx>>8;
      wp2b[n*256+k] = (n<NL)? f2bf(Wp2[k*NL+n]) : (u16)0;
    }
    return;
  }
  if(b < 9536){
    int wave = t>>6, lane = t&63;
    int i0 = (((b-1344)*4 + wave)<<1);
    float4 a0 = ((const float4*)(x + (size_t)i0*256))[lane];
    float4 a1 = ((const float4*)(x + (size_t)(i0+1)*256))[lane];
    float4 bb = ((const float4*)wmg)[lane];
    float s0 = a0.x*bb.x + a0.y*bb.y + a0.z*bb.z + a0.w*bb.w;
    float s1 = a1.x*bb.x + a1.y*bb.y + a1.z*bb.z + a1.w*bb.w;
    unsigned w0 = __builtin_amdgcn_cvt_pk_fp8_f32(a0.x, a0.y, 0, false);
    w0 = __builtin_amdgcn_cvt_pk_fp8_f32(a0.z, a0.w, w0, true);
    unsigned w1 = __builtin_amdgcn_cvt_pk_fp8_f32(a1.x, a1.y, 0, false);
    w1 = __builtin_amdgcn_cvt_pk_fp8_f32(a1.z, a1.w, w1, true);
    *(unsigned*)(xb8 + (size_t)i0*256 + lane*4) = w0;
    *(unsigned*)(xb8 + (size_t)(i0+1)*256 + lane*4) = w1;
    #pragma unroll
    for(int o=32;o;o>>=1){ s0 += __shfl_down(s0,o); s1 += __shfl_down(s1,o); }
    if(lane==0){ cf[i0]=silu_f(s0); cf[i0+1]=silu_f(s1); }
    return;
  }
  if(b < 11584){
    // radix pass 1: bin edges by dst>>8; pairs stay L2-resident (2.6MB)
    int e = (b-9536)*256 + t;
    if(e<NE){
      int src = ei[e], dst = ei[NE+e];
      int bin = dst>>8;
      int cur = atomicAdd(&bincur[bin],1);
      if(cur<BCAP) pairs[(size_t)bin*BCAP+cur] = ((unsigned)(dst&255)<<16) | (unsigned)src;
    }
    return;
  }
  // ---- kab: 4 graphs per block ----
  int bb2 = b - 11584;
  int wid = (bb2<<2) + (t>>6);
  int lane = t & 63;
  int s0 = gstart[wid], s1 = gstart[wid+1];
  const double L0 =  2.3025850929940456840;  // ln 10
  const double L1 = -4.6051701859880913680;  // ln 0.01
  float sg = (float)exp(L0 + (double)nl[wid]*(L1-L0)/49.0);
  if(lane==0) sigg[wid]=sg;

  float sx=0,sy=0,sz=0, tx=0,ty=0,tz=0;
  for(int i=s0+lane;i<s1;i+=64){
    float px=pos[3*i],py=pos[3*i+1],pz=pos[3*i+2];
    sx+=px; sy+=py; sz+=pz;
    tx+=px+noise[3*i]*sg; ty+=py+noise[3*i+1]*sg; tz+=pz+noise[3*i+2]*sg;
  }
  WRED(sx); WRED(sy); WRED(sz); WRED(tx); WRED(ty); WRED(tz);
  float invc = 1.f/fmaxf((float)(s1-s0),1.f);
  float cx=sx*invc, cy=sy*invc, cz=sz*invc;
  float pcx=tx*invc, pcy=ty*invc, pcz=tz*invc;

  float h00=0,h01=0,h02=0,h10=0,h11=0,h12=0,h20=0,h21=0,h22=0;
  for(int i=s0+lane;i<s1;i+=64){
    float px=pos[3*i],py=pos[3*i+1],pz=pos[3*i+2];
    float a0=px+noise[3*i]*sg-pcx, a1=py+noise[3*i+1]*sg-pcy, a2=pz+noise[3*i+2]*sg-pcz;
    float b0=px-cx, b1=py-cy, b2=pz-cz;
    h00+=a0*b0; h01+=a0*b1; h02+=a0*b2;
    h10+=a1*b0; h11+=a1*b1; h12+=a1*b2;
    h20+=a2*b0; h21+=a2*b1; h22+=a2*b2;
  }
  WRED(h00); WRED(h01); WRED(h02); WRED(h10); WRED(h11); WRED(h12);
  WRED(h20); WRED(h21); WRED(h22);

  float X[3][3] = {{h00,h10,h20},{h01,h11,h21},{h02,h12,h22}};
  float nf=0.f;
  #pragma unroll
  for(int r=0;r<3;r++) for(int c=0;c<3;c++) nf += X[r][c]*X[r][c];
  nf = sqrtf(nf);
  if(nf < 1e-20f){
    #pragma unroll
    for(int r=0;r<3;r++) for(int c=0;c<3;c++) X[r][c]=(r==c)?1.f:0.f;
  } else {
    float s0f=1.f/nf;
    #pragma unroll
    for(int r=0;r<3;r++) for(int c=0;c<3;c++) X[r][c]*=s0f;
    for(int it=0; it<30; ++it){
      float a=X[0][0],bq=X[0][1],c=X[0][2];
      float d=X[1][0],e=X[1][1],f=X[1][2];
      float gg=X[2][0],h=X[2][1],ii=X[2][2];
      float A_= e*ii-f*h, B_=-(d*ii-f*gg), C_= d*h-e*gg;
      float D_=-(bq*ii-c*h), E_= a*ii-c*gg, F_=-(a*h-bq*gg);
      float G_= bq*f-c*e,  H_=-(a*f-c*d),  I_= a*e-bq*d;
      float det = a*A_ + bq*B_ + c*C_;
      if(!(fabsf(det) > 1e-25f)){
        if(it==0){
          for(int r=0;r<3;r++) for(int cc=0;cc<3;cc++) X[r][cc]=(r==cc)?1.f:0.f;
        }
        break;
      }
      float si = 0.5f/det;
      float Y00=0.5f*a + si*A_, Y01=0.5f*bq + si*B_, Y02=0.5f*c + si*C_;
      float Y10=0.5f*d + si*D_, Y11=0.5f*e + si*E_, Y12=0.5f*f + si*F_;
      float Y20=0.5f*gg+ si*G_, Y21=0.5f*h + si*H_, Y22=0.5f*ii+ si*I_;
      X[0][0]=Y00; X[0][1]=Y01; X[0][2]=Y02;
      X[1][0]=Y10; X[1][1]=Y11; X[1][2]=Y12;
      X[2][0]=Y20; X[2][1]=Y21; X[2][2]=Y22;
    }
  }
  float T0 = cx - (X[0][0]*pcx + X[0][1]*pcy + X[0][2]*pcz);
  float T1 = cy - (X[1][0]*pcx + X[1][1]*pcy + X[1][2]*pcz);
  float T2 = cz - (X[2][0]*pcx + X[2][1]*pcy + X[2][2]*pcz);
  float is = 1.f/sg;
  for(int i=s0+lane;i<s1;i+=64){
    float px=pos[3*i],py=pos[3*i+1],pz=pos[3*i+2];
    float qx=px+noise[3*i]*sg, qy=py+noise[3*i+1]*sg, qz=pz+noise[3*i+2]*sg;
    float ox = X[0][0]*qx + X[0][1]*qy + X[0][2]*qz + T0;
    float oy = X[1][0]*qx + X[1][1]*qy + X[1][2]*qz + T1;
    float oz = X[2][0]*qx + X[2][1]*qy + X[2][2]*qz + T2;
    posp[3*i]=ox; posp[3*i+1]=oy; posp[3*i+2]=oz;
    target[3*i]=(px-ox)*is; target[3*i+1]=(py-oy)*is; target[3*i+2]=(pz-oz)*is;
  }
}

// =========== k_pass2: per-bin bucket build (dest window = 256 nodes, L2-local) ===========
__global__ void k_pass2(const int* __restrict__ bincur, const unsigned* __restrict__ pairs,
                        int* __restrict__ cnt_e, u16* __restrict__ elist){
  int bin = blockIdx.x;
  int n = min(bincur[bin], BCAP);
  for(int i=threadIdx.x; i<n; i+=256){
    unsigned p = pairs[(size_t)bin*BCAP+i];
    int dst = (bin<<8) | (int)(p>>16);
    int src = (int)(p & 0xFFFFu);
    int slot = atomicAdd(&cnt_e[dst],1);
    if(slot<CAP) elist[(size_t)dst*CAP+slot] = (u16)src;
  }
}

// =========== k_ge: gather (bucket CSR, u16) | eloss ===========
// blocks: [0,16384) gather, 4 nodes/block | [16384,16640) eloss
__global__ void k_ge(const u8* __restrict__ xb8, const int* __restrict__ cnt_e,
                     const u16* __restrict__ elist, u8* __restrict__ xs8,
                     const float* __restrict__ posp, const float* __restrict__ cf,
                     const float* __restrict__ target, const float* __restrict__ sigg,
                     const int* __restrict__ n2g, float* __restrict__ accum){
  int b = blockIdx.x, t = threadIdx.x;
  if(b < 16384){
    int lane = t & 63;
    int c = b*4 + (t>>6);
    int deg = min(cnt_e[c], CAP);
    const u16* el = elist + (size_t)c*CAP;
    float a0=0.f,a1=0.f,a2=0.f,a3=0.f;
    int e=0;
    for(; e+3<deg; e+=4){
      int r0=el[e], r1=el[e+1], r2=el[e+2], r3=el[e+3];
      unsigned w0 = *(const unsigned*)(xb8 + (size_t)r0*256 + lane*4);
      unsigned w1 = *(const unsigned*)(xb8 + (size_t)r1*256 + lane*4);
      unsigned w2 = *(const unsigned*)(xb8 + (size_t)r2*256 + lane*4);
      unsigned w3 = *(const unsigned*)(xb8 + (size_t)r3*256 + lane*4);
      float4 v0 = e4m3x4(w0), v1 = e4m3x4(w1), v2 = e4m3x4(w2), v3 = e4m3x4(w3);
      a0 += (v0.x+v1.x)+(v2.x+v3.x); a1 += (v0.y+v1.y)+(v2.y+v3.y);
      a2 += (v0.z+v1.z)+(v2.z+v3.z); a3 += (v0.w+v1.w)+(v2.w+v3.w);
    }
    for(; e<deg; ++e){
      unsigned w0 = *(const unsigned*)(xb8 + (size_t)el[e]*256 + lane*4);
      float4 v0 = e4m3x4(w0);
      a0+=v0.x; a1+=v0.y; a2+=v0.z; a3+=v0.w;
    }
    unsigned w = __builtin_amdgcn_cvt_pk_fp8_f32(a0, a1, 0, false);
    w = __builtin_amdgcn_cvt_pk_fp8_f32(a2, a3, w, true);
    *(unsigned*)(xs8 + (size_t)c*256 + lane*4) = w;
  } else {
    int i = (b-16384)*256 + t;
    float s=0.f;
    {
      int deg = min(cnt_e[i], CAP);
      const u16* el = elist + (size_t)i*CAP;
      float px=posp[i*3+0], py=posp[i*3+1], pz=posp[i*3+2];
      float dx=0.f, dy=0.f, dz=0.f;
      for(int e=0;e<deg;e++){
        int r=el[e];
        float c=cf[r];
        dx += (posp[r*3+0]-px)*c;
        dy += (posp[r*3+1]-py)*c;
        dz += (posp[r*3+2]-pz)*c;
      }
      float is = 1.f/sigg[n2g[i]];
      float d0 = dx*is - target[i*3+0];
      float d1 = dy*is - target[i*3+1];
      float d2 = dz*is - target[i*3+2];
      s = d0*d0+d1*d1+d2*d2;
    }
    #pragma unroll
    for(int o=32;o;o>>=1) s += __shfl_down(s,o);
    if((t&63)==0) atomicAdd(&accum[0], s);
  }
}

// ---------------- fused fp8 node GEMM chain (r12 + T5 setprio) ----------------
__global__ __launch_bounds__(512) void gemmF8(
    const u8* __restrict__ A1, const u8* __restrict__ A2,
    const u8* __restrict__ Wn, const u8* __restrict__ Wm,
    const u8* __restrict__ Wd, const float* __restrict__ bd1,
    u8* __restrict__ outb){
  __shared__ u8 Bs[32768];   // 2x16KB ping-pong; whole 32KB reused by epilogue
  __shared__ u8 XL[32768];   // per-wave xl (4KB each)
  int t = threadIdx.x;
  int wave = t>>6, lane = t&63;
  int lr = lane&15, lkgrp = lane>>4, lk8 = lkgrp*8;
  int m0 = blockIdx.x*128 + wave*16;
  char* xlw = (char*)XL + wave*4096;
  int row_t = t>>2, col_t = (t&3)*32;   // staging: 32B per thread

  f32x4 acc[16];
  #pragma unroll
  for(int i=0;i<16;i++) acc[i]=(f32x4){0.f,0.f,0.f,0.f};

  short8 pre0, pre1;
  auto preload = [&](int u){
    const u8* W = (u>=8)? Wd : (((u>>1)&1)? Wm : Wn);
    int h  = (u>=8)? ((u>>1)&1) : (u>>2);
    int kh = u&1;
    const u8* s = W + (size_t)(h*128 + row_t)*256 + kh*128 + col_t;
    pre0 = *(const short8*)(s);
    pre1 = *(const short8*)(s+16);
  };
  auto commit = [&](int p){
    char* d = (char*)Bs + p*16384 + row_t*128 + col_t;
    *(short8*)(d)    = pre0;
    *(short8*)(d+16) = pre1;
  };

  preload(0); commit(0);
  #pragma unroll
  for(int u=0; u<12; ++u){
    if(u<11) preload(u+1);
    __syncthreads();                       // buf[u&1] ready
    const char* buf = (const char*)Bs + (u&1)*16384;
    int kh = u&1;
    int hsel = (u>=8)? ((u>>1)&1) : (u>>2);
    __builtin_amdgcn_s_setprio(1);
    if(u<8){
      int m = (u>>1)&1;
      const u8* Ab = (m==0? A1 : A2) + (size_t)(m0+lr)*256;
      #pragma unroll
      for(int kq=0;kq<4;++kq){
        int k0 = kh*128 + kq*32;
        long bx = *(const long*)(Ab + k0 + lk8);
        #pragma unroll
        for(int nt=0;nt<8;++nt){
          unsigned row = nt*16+lr;
          unsigned byte = (row*128u + kq*32 + lk8) ^ ((row&15u)<<3);
          long a = *(const long*)(buf + byte);
          acc[hsel*8+nt] = __builtin_amdgcn_mfma_f32_16x16x32_fp8_fp8(a,bx,acc[hsel*8+nt],0,0,0);
        }
      }
    } else {
      #pragma unroll
      for(int kq=0;kq<4;++kq){
        int k0 = kh*128 + kq*32;
        unsigned ab = (((unsigned)lr<<8) + k0 + lk8) ^ ((lr&15u)<<3);
        long bx = *(const long*)(xlw + ab);
        #pragma unroll
        for(int nt=0;nt<8;++nt){
          unsigned row = nt*16+lr;
          unsigned byte = (row*128u + kq*32 + lk8) ^ ((row&15u)<<3);
          long a = *(const long*)(buf + byte);
          acc[hsel*8+nt] = __builtin_amdgcn_mfma_f32_16x16x32_fp8_fp8(a,bx,acc[hsel*8+nt],0,0,0);
        }
      }
    }
    __builtin_amdgcn_s_setprio(0);
    if(u<11) commit((u&1)^1);
    if(u==3){
      #pragma unroll
      for(int nt=0;nt<8;++nt){
        f32x4 v = acc[nt];
        unsigned pk = __builtin_amdgcn_cvt_pk_fp8_f32(silu_f(v[0]), silu_f(v[1]), 0, false);
        pk = __builtin_amdgcn_cvt_pk_fp8_f32(silu_f(v[2]), silu_f(v[3]), pk, true);
        unsigned byte = (((unsigned)lr<<8) + nt*16 + lkgrp*4) ^ ((lr&15u)<<3);
        *(unsigned*)(xlw + byte) = pk;
      }
    }
    if(u==7){
      #pragma unroll
      for(int nt=0;nt<8;++nt){
        f32x4 v = acc[8+nt];
        unsigned pk = __builtin_amdgcn_cvt_pk_fp8_f32(silu_f(v[0]), silu_f(v[1]), 0, false);
        pk = __builtin_amdgcn_cvt_pk_fp8_f32(silu_f(v[2]), silu_f(v[3]), pk, true);
        unsigned byte = (((unsigned)lr<<8) + 128 + nt*16 + lkgrp*4) ^ ((lr&15u)<<3);
        *(unsigned*)(xlw + byte) = pk;
      }
      #pragma unroll
      for(int i=0;i<16;i++) acc[i]=(f32x4){0.f,0.f,0.f,0.f};
    }
  }

  // epilogue: h1 = silu(acc + bd1) -> Bs (dword, swizzled) -> coalesced 8B copy
  __syncthreads();
  #pragma unroll
  for(int h=0;h<2;++h){
    #pragma unroll
    for(int nt=0;nt<8;++nt){
      f32x4 v = acc[h*8+nt];
      int F = h*128 + nt*16 + lkgrp*4;
      unsigned pk = __builtin_amdgcn_cvt_pk_fp8_f32(silu_f(v[0]+bd1[F+0]), silu_f(v[1]+bd1[F+1]), 0, false);
      pk = __builtin_amdgcn_cvt_pk_fp8_f32(silu_f(v[2]+bd1[F+2]), silu_f(v[3]+bd1[F+3]), pk, true);
      unsigned row = (unsigned)(wave*16 + lr);
      unsigned byte = ((row<<8) + (unsigned)F) ^ ((row&15u)<<3);
      *(unsigned*)((char*)Bs + byte) = pk;
    }
  }
  __syncthreads();
  #pragma unroll
  for(int it=0; it<8; ++it){
    unsigned byte = (unsigned)(it*512 + t)*8;
    unsigned src = byte ^ (((byte>>8)&15u)<<3);
    long v = *(const long*)((const char*)Bs + src);
    *(long*)(outb + (size_t)blockIdx.x*32768 + byte) = v;
  }
}

// ---------------- per-graph seg-sum of h1 (fp8 in, bf16 out), 4 graphs/block ----------------
__global__ void k_sg8(const u8* __restrict__ h18, const int* __restrict__ gstart,
                      u16* __restrict__ sgb){
  int lane = threadIdx.x&63;
  int g = blockIdx.x*4 + (threadIdx.x>>6);
  int s0=gstart[g], s1=gstart[g+1];
  float a0=0.f,a1=0.f,a2=0.f,a3=0.f;
  for(int i=s0;i<s1;i++){
    unsigned w = *(const unsigned*)(h18 + (size_t)i*256 + lane*4);
    float4 v = e4m3x4(w);
    a0+=v.x; a1+=v.y; a2+=v.z; a3+=v.w;
  }
  us4 o; o.x=f2bf(a0); o.y=f2bf(a1); o.z=f2bf(a2); o.w=f2bf(a3);
  *(us4*)(sgb + (size_t)g*256 + lane*4) = o;
}

// ---------------- fused head: xg -> h -> logits+CE -> (last block) final ----------------
__global__ __launch_bounds__(256) void k_head3(const u16* __restrict__ sgb,
        const int* __restrict__ gstart, const float* __restrict__ bd2,
        const u16* __restrict__ wd2b, const u16* __restrict__ wpeb,
        const float* __restrict__ bp1, const u16* __restrict__ wp2b,
        const float* __restrict__ bp2, const int* __restrict__ nlv,
        float* __restrict__ accum, int* __restrict__ done,
        float* __restrict__ out){
  __shared__ u16 S[64*256];
  int t = threadIdx.x;
  int wave = t>>6, lane = t&63;
  int lr = lane&15, lkgrp = lane>>4, lk = lkgrp*8;
  int g0 = blockIdx.x*64;
  int rw = wave*16;

  f32x4 acc[16];
  #pragma unroll
  for(int nt=0;nt<16;nt++) acc[nt]=(f32x4){0.f,0.f,0.f,0.f};
  #pragma unroll
  for(int k0=0;k0<256;k0+=32){
    short8 a = *(const short8*)(sgb + (size_t)(g0+rw+lr)*256 + k0 + lk);
    #pragma unroll
    for(int nt=0;nt<16;nt++){
      short8 b = *(const short8*)(wd2b + (size_t)(nt*16+lr)*256 + k0 + lk);
      acc[nt] = __builtin_amdgcn_mfma_f32_16x16x32_bf16(a,b,acc[nt],0,0,0);
    }
  }
  #pragma unroll
  for(int j=0;j<4;j++){
    unsigned gl = rw + lkgrp*4 + j;
    float cnt = (float)(gstart[g0+gl+1]-gstart[g0+gl]);
    #pragma unroll
    for(int nt=0;nt<16;nt++){
      int c = nt*16+lr;
      float v = acc[nt][j] + cnt*bd2[c];
      *(u16*)((char*)S + ((((gl<<9) + c*2)) ^ ((gl&7u)<<4))) = f2bf(v);
    }
  }

  #pragma unroll
  for(int nt=0;nt<16;nt++) acc[nt]=(f32x4){0.f,0.f,0.f,0.f};
  #pragma unroll
  for(int k0=0;k0<256;k0+=32){
    unsigned row = rw+lr;
    short8 a = *(const short8*)((char*)S + (((row<<9) + (k0+lk)*2) ^ ((row&7u)<<4)));
    #pragma unroll
    for(int nt=0;nt<16;nt++){
      short8 b = *(const short8*)(wpeb + (size_t)(nt*16+lr)*256 + k0 + lk);
      acc[nt] = __builtin_amdgcn_mfma_f32_16x16x32_bf16(a,b,acc[nt],0,0,0);
    }
  }
  #pragma unroll
  for(int j=0;j<4;j++){
    unsigned gl = rw + lkgrp*4 + j;
    #pragma unroll
    for(int nt=0;nt<16;nt++){
      int c = nt*16+lr;
      float v = silu_f(acc[nt][j] + bp1[c]);
      *(u16*)((char*)S + ((((gl<<9) + c*2)) ^ ((gl&7u)<<4))) = f2bf(v);
    }
  }

  #pragma unroll
  for(int nt=0;nt<4;nt++) acc[nt]=(f32x4){0.f,0.f,0.f,0.f};
  #pragma unroll
  for(int k0=0;k0<256;k0+=32){
    unsigned row = rw+lr;
    short8 a = *(const short8*)((char*)S + (((row<<9) + (k0+lk)*2) ^ ((row&7u)<<4)));
    #pragma unroll
    for(int nt=0;nt<4;nt++){
      short8 b = *(const short8*)(wp2b + (size_t)(nt*16+lr)*256 + k0 + lk);
      acc[nt] = __builtin_amdgcn_mfma_f32_16x16x32_bf16(a,b,acc[nt],0,0,0);
    }
  }
  float bp[4];
  #pragma unroll
  for(int nt=0;nt<4;nt++){
    int c = nt*16+lr;
    bp[nt] = (c<NL)? bp2[c] : 0.f;
  }
  float s = 0.f;
  #pragma unroll
  for(int j=0;j<4;j++){
    int g = g0 + rw + lkgrp*4 + j;
    int tgt = nlv[g];
    float mx = -1e30f, pk = 0.f;
    float lg[4];
    #pragma unroll
    for(int nt=0;nt<4;nt++){
      int c = nt*16+lr;
      lg[nt] = (c<NL)? (acc[nt][j] + bp[nt]) : -1e30f;
      mx = fmaxf(mx, lg[nt]);
      if(c==tgt) pk = lg[nt];
    }
    #pragma unroll
    for(int o=1;o<16;o<<=1) mx = fmaxf(mx, __shfl_xor(mx,o));
    float se = 0.f;
    #pragma unroll
    for(int nt=0;nt<4;nt++) se += __expf(lg[nt]-mx);
    #pragma unroll
    for(int o=1;o<16;o<<=1) se += __shfl_xor(se,o);
    #pragma unroll
    for(int o=1;o<16;o<<=1) pk += __shfl_xor(pk,o);
    s += logf(se)+mx - pk;
  }
  if(lr==0) atomicAdd(&accum[1], s);
  __syncthreads();
  if(t==0){
    __threadfence();
    int old = atomicAdd(done, 1);
    if(old == 31){                          // last of 32 blocks
      float l0 = atomicAdd(&accum[0], 0.0f);
      float l1 = atomicAdd(&accum[1], 0.0f);
      out[0] = l0/(float)NG;
      out[1] = l1/(float)NG;
    }
  }
}

// ---------------- launcher ----------------
extern "C" void kernel_launch(void* const* d_in, const int* in_sizes, int n_in,
                              void* d_out, int out_size, void* d_ws, size_t ws_size,
                              hipStream_t stream){
  (void)in_sizes; (void)n_in; (void)out_size; (void)ws_size;
  const float* x      = (const float*)d_in[0];
  const float* pos    = (const float*)d_in[1];
  const float* noise  = (const float*)d_in[2];
  const int*   n2g    = (const int*)d_in[3];
  const int*   ei     = (const int*)d_in[4];
  const int*   nl     = (const int*)d_in[5];
  const float* W_node = (const float*)d_in[6];
  const float* W_msg  = (const float*)d_in[7];
  const float* w_gate = (const float*)d_in[8];
  const float* Wd1    = (const float*)d_in[9];
  const float* bd1    = (const float*)d_in[10];
  const float* Wd2    = (const float*)d_in[11];
  const float* bd2    = (const float*)d_in[12];
  const float* Wp1    = (const float*)d_in[17];
  const float* bp1    = (const float*)d_in[18];
  const float* Wp2    = (const float*)d_in[19];
  const float* bp2    = (const float*)d_in[20];
  float* out = (float*)d_out;

  char* w = (char*)d_ws;
  size_t off = 0;
  auto alloc = [&](size_t bytes)->void*{
    void* p = w + off;
    off += (bytes + 255) & ~(size_t)255;
    return p;
  };

  // --- zeroed region ---
  size_t zstart = off;
  int*   cnt_e   = (int*)alloc((size_t)NN*4);
  int*   bincur  = (int*)alloc((size_t)256*4);
  float* accum   = (float*)alloc(2*4);
  int*   done    = (int*)alloc(4);
  size_t zend = off;

  // --- other buffers ---
  u8*   xb8  = (u8*)alloc((size_t)NN*HD);
  u8*   xs8  = (u8*)alloc((size_t)NN*HD);
  u8*   h18  = (u8*)alloc((size_t)NN*HD);
  u16*  sgb  = (u16*)alloc((size_t)NG*HD*2);
  float* sigg   = (float*)alloc((size_t)NG*4);
  float* posp   = (float*)alloc((size_t)NN*3*4);
  float* target = (float*)alloc((size_t)NN*3*4);
  float* cf     = (float*)alloc((size_t)NN*4);
  int*  gstart  = (int*)alloc((size_t)(NG+1)*4);
  u16*  elist   = (u16*)alloc((size_t)NN*CAP*2);        // 8MB bucket CSR (u16 ids)
  unsigned* pairs = (unsigned*)alloc((size_t)256*BCAP*4); // 2.6MB radix bins
  u8*   wn8     = (u8*)alloc((size_t)HD*HD);
  u8*   wm8     = (u8*)alloc((size_t)HD*HD);
  u8*   wd18    = (u8*)alloc((size_t)HD*HD);
  u16*  wd2b    = (u16*)alloc((size_t)HD*HD*2);
  u16*  wpeb    = (u16*)alloc((size_t)HD*HD*2);
  u16*  wp2b    = (u16*)alloc((size_t)64*HD*2);
  float* wmg    = (float*)alloc((size_t)HD*4);

  (void)hipMemsetAsync(w+zstart, 0, zend-zstart, stream);

  // pre: wmg | graph boundaries
  k_pre   <<<258,256,0,stream>>>(W_msg,w_gate,n2g,wmg,gstart);

  // front3: wall | prep8 | radix-pass1 | kab
  k_front3<<<12096,256,0,stream>>>(x,ei,W_node,W_msg,Wd1,Wd2,Wp1,Wp2,
                                   pos,noise,gstart,nl,wmg,
                                   wn8,wm8,wd18,wd2b,wpeb,wp2b,
                                   xb8,cf,bincur,pairs,sigg,posp,target);

  // radix pass2: bucket build (L2-window-local writes)
  k_pass2 <<<256,256,0,stream>>>(bincur,pairs,cnt_e,elist);

  // gather | eloss
  k_ge    <<<16640,256,0,stream>>>(xb8,cnt_e,elist,xs8,
                                   posp,cf,target,sigg,n2g,accum);

  // GNN node chain
  gemmF8  <<<512,512,0,stream>>>(xb8,xs8,wn8,wm8,wd18,bd1,h18);

  // graph rep + head (ce, fused final)
  k_sg8   <<<512,256,0,stream>>>(h18,gstart,sgb);
  k_head3 <<<NG/64,256,0,stream>>>(sgb,gstart,bd2,wd2b,wpeb,bp1,wp2b,bp2,nl,
                                   accum,done,out);
}

// Round 16
// 227.514 us; speedup vs baseline: 1.9495x; 1.9495x over previous
//
#include <hip/hip_runtime.h>
#include <math.h>

#define NN 65536   // nodes
#define NE 524288  // edges
#define NG 2048    // graphs
#define HD 256     // hidden
#define NL 50      // noise levels
#define CAP 64     // bucket capacity per node (Poisson(8): P(deg>64) ~ 1e-38)

typedef unsigned short u16;
typedef unsigned char u8;
typedef __attribute__((ext_vector_type(8))) short short8;
typedef __attribute__((ext_vector_type(4))) float f32x4;
typedef __attribute__((ext_vector_type(4))) unsigned short us4;

__device__ __forceinline__ float bf2f(u16 h){
  union{unsigned int u; float f;} v; v.u = ((unsigned int)h)<<16; return v.f;
}
__device__ __forceinline__ u16 f2bf(float f){
  union{float f; unsigned int u;} v; v.f=f;
  return (u16)((v.u + 0x7FFFu + ((v.u>>16)&1u))>>16);
}
__device__ __forceinline__ float silu_f(float v){ return v/(1.0f+__expf(-v)); }
__device__ __forceinline__ u8 f2e4m3(float v){
  return (u8)__builtin_amdgcn_cvt_pk_fp8_f32(v, v, 0, false);
}
__device__ __forceinline__ float4 e4m3x4(unsigned w){
  float4 r;
  r.x = __builtin_amdgcn_cvt_f32_fp8(w, 0);
  r.y = __builtin_amdgcn_cvt_f32_fp8(w, 1);
  r.z = __builtin_amdgcn_cvt_f32_fp8(w, 2);
  r.w = __builtin_amdgcn_cvt_f32_fp8(w, 3);
  return r;
}

#define WRED(v) { v += __shfl_xor(v,1); v += __shfl_xor(v,2); v += __shfl_xor(v,4); \
                  v += __shfl_xor(v,8); v += __shfl_xor(v,16); v += __shfl_xor(v,32); }

// =========== k_pre: wmg (block 0) | graph boundaries (blocks 1..257) ===========
__global__ void k_pre(const float* __restrict__ Wm, const float* __restrict__ wgate,
                      const int* __restrict__ n2g,
                      float* __restrict__ wmg, int* __restrict__ gstart){
  int b = blockIdx.x, t = threadIdx.x;
  if(b==0){
    float s=0.f;
    for(int j=0;j<256;j++) s += Wm[t*256+j]*wgate[j];
    wmg[t]=s;
  } else {
    int i = (b-1)*256 + t;
    if(i>NN) return;
    int cur  = (i<NN)? n2g[i] : NG;
    int prev = (i==0)? -1 : n2g[i-1];
    for(int g=prev+1; g<=cur; ++g) gstart[g]=i;
  }
}

// =========== k_front3: wall | prep8(2 rows/wave) | count-scatter | kab ===========
// blocks: [0,1344) wall | [1344,9536) prep8 | [9536,11584) countscatter |
//         [11584,12096) kab (4 graphs/block)
__global__ __launch_bounds__(256) void k_front3(
        const float* __restrict__ x, const int* __restrict__ ei,
        const float* __restrict__ Wn, const float* __restrict__ Wm,
        const float* __restrict__ Wd1, const float* __restrict__ Wd2,
        const float* __restrict__ Wp1, const float* __restrict__ Wp2,
        const float* __restrict__ pos, const float* __restrict__ noise,
        const int* __restrict__ gstart, const int* __restrict__ nl,
        const float* __restrict__ wmg,
        u8* __restrict__ wn8, u8* __restrict__ wm8, u8* __restrict__ wd18,
        u16* __restrict__ wd2b, u16* __restrict__ wpeb, u16* __restrict__ wp2b,
        u8* __restrict__ xb8, float* __restrict__ cf,
        int* __restrict__ cnt_e, u16* __restrict__ elist,
        float* __restrict__ sigg, float* __restrict__ posp,
        float* __restrict__ target){
  int b = blockIdx.x, t = threadIdx.x;
  if(b < 1344){
    if(b < 768){
      int m = b>>8;
      int idx = (b&255)*256 + t;
      int k = idx>>8, n = idx&255;
      const float* W = (m==0)? Wn : (m==1)? Wm : Wd1;
      u8* O = (m==0)? wn8 : (m==1)? wm8 : wd18;
      unsigned a = (unsigned)(n*256+k);
      O[a ^ ((unsigned)(n&15)<<3)] = f2e4m3(W[k*256+n]);   // pre-swizzled
    } else if(b < 1024){
      int idx = (b-768)*256 + t; int k=idx>>8, n=idx&255;
      wd2b[n*256+k] = f2bf(Wd2[k*256+n]);
    } else if(b < 1280){
      int idx = (b-1024)*256 + t; int k=idx>>8, n=idx&255;
      wpeb[n*256+k] = f2bf(Wp1[k*256+n] + Wp1[(k+256)*256+n]);
    } else {
      int idx = (b-1280)*256 + t; int k=idx&255, n=idx>>8;
      wp2b[n*256+k] = (n<NL)? f2bf(Wp2[k*NL+n]) : (u16)0;
    }
    return;
  }
  if(b < 9536){
    int wave = t>>6, lane = t&63;
    int i0 = (((b-1344)*4 + wave)<<1);
    float4 a0 = ((const float4*)(x + (size_t)i0*256))[lane];
    float4 a1 = ((const float4*)(x + (size_t)(i0+1)*256))[lane];
    float4 bb = ((const float4*)wmg)[lane];
    float s0 = a0.x*bb.x + a0.y*bb.y + a0.z*bb.z + a0.w*bb.w;
    float s1 = a1.x*bb.x + a1.y*bb.y + a1.z*bb.z + a1.w*bb.w;
    unsigned w0 = __builtin_amdgcn_cvt_pk_fp8_f32(a0.x, a0.y, 0, false);
    w0 = __builtin_amdgcn_cvt_pk_fp8_f32(a0.z, a0.w, w0, true);
    unsigned w1 = __builtin_amdgcn_cvt_pk_fp8_f32(a1.x, a1.y, 0, false);
    w1 = __builtin_amdgcn_cvt_pk_fp8_f32(a1.z, a1.w, w1, true);
    *(unsigned*)(xb8 + (size_t)i0*256 + lane*4) = w0;
    *(unsigned*)(xb8 + (size_t)(i0+1)*256 + lane*4) = w1;
    #pragma unroll
    for(int o=32;o;o>>=1){ s0 += __shfl_down(s0,o); s1 += __shfl_down(s1,o); }
    if(lane==0){ cf[i0]=silu_f(s0); cf[i0+1]=silu_f(s1); }
    return;
  }
  if(b < 11584){
    int e = (b-9536)*256 + t;
    if(e<NE){
      int c = ei[NE+e];
      int slot = atomicAdd(&cnt_e[c],1);
      if(slot<CAP) elist[(size_t)c*CAP+slot] = (u16)ei[e];
    }
    return;
  }
  // ---- kab: 4 graphs per block ----
  int bb2 = b - 11584;
  int wid = (bb2<<2) + (t>>6);
  int lane = t & 63;
  int s0 = gstart[wid], s1 = gstart[wid+1];
  const double L0 =  2.3025850929940456840;  // ln 10
  const double L1 = -4.6051701859880913680;  // ln 0.01
  float sg = (float)exp(L0 + (double)nl[wid]*(L1-L0)/49.0);
  if(lane==0) sigg[wid]=sg;

  float sx=0,sy=0,sz=0, tx=0,ty=0,tz=0;
  for(int i=s0+lane;i<s1;i+=64){
    float px=pos[3*i],py=pos[3*i+1],pz=pos[3*i+2];
    sx+=px; sy+=py; sz+=pz;
    tx+=px+noise[3*i]*sg; ty+=py+noise[3*i+1]*sg; tz+=pz+noise[3*i+2]*sg;
  }
  WRED(sx); WRED(sy); WRED(sz); WRED(tx); WRED(ty); WRED(tz);
  float invc = 1.f/fmaxf((float)(s1-s0),1.f);
  float cx=sx*invc, cy=sy*invc, cz=sz*invc;
  float pcx=tx*invc, pcy=ty*invc, pcz=tz*invc;

  float h00=0,h01=0,h02=0,h10=0,h11=0,h12=0,h20=0,h21=0,h22=0;
  for(int i=s0+lane;i<s1;i+=64){
    float px=pos[3*i],py=pos[3*i+1],pz=pos[3*i+2];
    float a0=px+noise[3*i]*sg-pcx, a1=py+noise[3*i+1]*sg-pcy, a2=pz+noise[3*i+2]*sg-pcz;
    float b0=px-cx, b1=py-cy, b2=pz-cz;
    h00+=a0*b0; h01+=a0*b1; h02+=a0*b2;
    h10+=a1*b0; h11+=a1*b1; h12+=a1*b2;
    h20+=a2*b0; h21+=a2*b1; h22+=a2*b2;
  }
  WRED(h00); WRED(h01); WRED(h02); WRED(h10); WRED(h11); WRED(h12);
  WRED(h20); WRED(h21); WRED(h22);

  float X[3][3] = {{h00,h10,h20},{h01,h11,h21},{h02,h12,h22}};
  float nf=0.f;
  #pragma unroll
  for(int r=0;r<3;r++) for(int c=0;c<3;c++) nf += X[r][c]*X[r][c];
  nf = sqrtf(nf);
  if(nf < 1e-20f){
    #pragma unroll
    for(int r=0;r<3;r++) for(int c=0;c<3;c++) X[r][c]=(r==c)?1.f:0.f;
  } else {
    float s0f=1.f/nf;
    #pragma unroll
    for(int r=0;r<3;r++) for(int c=0;c<3;c++) X[r][c]*=s0f;
    for(int it=0; it<30; ++it){
      float a=X[0][0],bq=X[0][1],c=X[0][2];
      float d=X[1][0],e=X[1][1],f=X[1][2];
      float gg=X[2][0],h=X[2][1],ii=X[2][2];
      float A_= e*ii-f*h, B_=-(d*ii-f*gg), C_= d*h-e*gg;
      float D_=-(bq*ii-c*h), E_= a*ii-c*gg, F_=-(a*h-bq*gg);
      float G_= bq*f-c*e,  H_=-(a*f-c*d),  I_= a*e-bq*d;
      float det = a*A_ + bq*B_ + c*C_;
      if(!(fabsf(det) > 1e-25f)){
        if(it==0){
          for(int r=0;r<3;r++) for(int cc=0;cc<3;cc++) X[r][cc]=(r==cc)?1.f:0.f;
        }
        break;
      }
      float si = 0.5f/det;
      float Y00=0.5f*a + si*A_, Y01=0.5f*bq + si*B_, Y02=0.5f*c + si*C_;
      float Y10=0.5f*d + si*D_, Y11=0.5f*e + si*E_, Y12=0.5f*f + si*F_;
      float Y20=0.5f*gg+ si*G_, Y21=0.5f*h + si*H_, Y22=0.5f*ii+ si*I_;
      X[0][0]=Y00; X[0][1]=Y01; X[0][2]=Y02;
      X[1][0]=Y10; X[1][1]=Y11; X[1][2]=Y12;
      X[2][0]=Y20; X[2][1]=Y21; X[2][2]=Y22;
    }
  }
  float T0 = cx - (X[0][0]*pcx + X[0][1]*pcy + X[0][2]*pcz);
  float T1 = cy - (X[1][0]*pcx + X[1][1]*pcy + X[1][2]*pcz);
  float T2 = cz - (X[2][0]*pcx + X[2][1]*pcy + X[2][2]*pcz);
  float is = 1.f/sg;
  for(int i=s0+lane;i<s1;i+=64){
    float px=pos[3*i],py=pos[3*i+1],pz=pos[3*i+2];
    float qx=px+noise[3*i]*sg, qy=py+noise[3*i+1]*sg, qz=pz+noise[3*i+2]*sg;
    float ox = X[0][0]*qx + X[0][1]*qy + X[0][2]*qz + T0;
    float oy = X[1][0]*qx + X[1][1]*qy + X[1][2]*qz + T1;
    float oz = X[2][0]*qx + X[2][1]*qy + X[2][2]*qz + T2;
    posp[3*i]=ox; posp[3*i+1]=oy; posp[3*i+2]=oz;
    target[3*i]=(px-ox)*is; target[3*i+1]=(py-oy)*is; target[3*i+2]=(pz-oz)*is;
  }
}

// =========== k_ge: gather (bucket CSR, u16) | eloss ===========
// blocks: [0,16384) gather, 4 nodes/block | [16384,16640) eloss
__global__ void k_ge(const u8* __restrict__ xb8, const int* __restrict__ cnt_e,
                     const u16* __restrict__ elist, u8* __restrict__ xs8,
                     const float* __restrict__ posp, const float* __restrict__ cf,
                     const float* __restrict__ target, const float* __restrict__ sigg,
                     const int* __restrict__ n2g, float* __restrict__ accum){
  int b = blockIdx.x, t = threadIdx.x;
  if(b < 16384){
    int lane = t & 63;
    int c = b*4 + (t>>6);
    int deg = min(cnt_e[c], CAP);
    const u16* el = elist + (size_t)c*CAP;
    float a0=0.f,a1=0.f,a2=0.f,a3=0.f;
    int e=0;
    for(; e+3<deg; e+=4){
      int r0=el[e], r1=el[e+1], r2=el[e+2], r3=el[e+3];
      unsigned w0 = *(const unsigned*)(xb8 + (size_t)r0*256 + lane*4);
      unsigned w1 = *(const unsigned*)(xb8 + (size_t)r1*256 + lane*4);
      unsigned w2 = *(const unsigned*)(xb8 + (size_t)r2*256 + lane*4);
      unsigned w3 = *(const unsigned*)(xb8 + (size_t)r3*256 + lane*4);
      float4 v0 = e4m3x4(w0), v1 = e4m3x4(w1), v2 = e4m3x4(w2), v3 = e4m3x4(w3);
      a0 += (v0.x+v1.x)+(v2.x+v3.x); a1 += (v0.y+v1.y)+(v2.y+v3.y);
      a2 += (v0.z+v1.z)+(v2.z+v3.z); a3 += (v0.w+v1.w)+(v2.w+v3.w);
    }
    for(; e<deg; ++e){
      unsigned w0 = *(const unsigned*)(xb8 + (size_t)el[e]*256 + lane*4);
      float4 v0 = e4m3x4(w0);
      a0+=v0.x; a1+=v0.y; a2+=v0.z; a3+=v0.w;
    }
    unsigned w = __builtin_amdgcn_cvt_pk_fp8_f32(a0, a1, 0, false);
    w = __builtin_amdgcn_cvt_pk_fp8_f32(a2, a3, w, true);
    *(unsigned*)(xs8 + (size_t)c*256 + lane*4) = w;
  } else {
    int i = (b-16384)*256 + t;
    float s=0.f;
    {
      int deg = min(cnt_e[i], CAP);
      const u16* el = elist + (size_t)i*CAP;
      float px=posp[i*3+0], py=posp[i*3+1], pz=posp[i*3+2];
      float dx=0.f, dy=0.f, dz=0.f;
      for(int e=0;e<deg;e++){
        int r=el[e];
        float c=cf[r];
        dx += (posp[r*3+0]-px)*c;
        dy += (posp[r*3+1]-py)*c;
        dz += (posp[r*3+2]-pz)*c;
      }
      float is = 1.f/sigg[n2g[i]];
      float d0 = dx*is - target[i*3+0];
      float d1 = dy*is - target[i*3+1];
      float d2 = dz*is - target[i*3+2];
      s = d0*d0+d1*d1+d2*d2;
    }
    #pragma unroll
    for(int o=32;o;o>>=1) s += __shfl_down(s,o);
    if((t&63)==0) atomicAdd(&accum[0], s);
  }
}

// ---------------- fused fp8 node GEMM chain (r12 + T5 setprio) ----------------
__global__ __launch_bounds__(512) void gemmF8(
    const u8* __restrict__ A1, const u8* __restrict__ A2,
    const u8* __restrict__ Wn, const u8* __restrict__ Wm,
    const u8* __restrict__ Wd, const float* __restrict__ bd1,
    u8* __restrict__ outb){
  __shared__ u8 Bs[32768];   // 2x16KB ping-pong; whole 32KB reused by epilogue
  __shared__ u8 XL[32768];   // per-wave xl (4KB each)
  int t = threadIdx.x;
  int wave = t>>6, lane = t&63;
  int lr = lane&15, lkgrp = lane>>4, lk8 = lkgrp*8;
  int m0 = blockIdx.x*128 + wave*16;
  char* xlw = (char*)XL + wave*4096;
  int row_t = t>>2, col_t = (t&3)*32;   // staging: 32B per thread

  f32x4 acc[16];
  #pragma unroll
  for(int i=0;i<16;i++) acc[i]=(f32x4){0.f,0.f,0.f,0.f};

  short8 pre0, pre1;
  auto preload = [&](int u){
    const u8* W = (u>=8)? Wd : (((u>>1)&1)? Wm : Wn);
    int h  = (u>=8)? ((u>>1)&1) : (u>>2);
    int kh = u&1;
    const u8* s = W + (size_t)(h*128 + row_t)*256 + kh*128 + col_t;
    pre0 = *(const short8*)(s);
    pre1 = *(const short8*)(s+16);
  };
  auto commit = [&](int p){
    char* d = (char*)Bs + p*16384 + row_t*128 + col_t;
    *(short8*)(d)    = pre0;
    *(short8*)(d+16) = pre1;
  };

  preload(0); commit(0);
  #pragma unroll
  for(int u=0; u<12; ++u){
    if(u<11) preload(u+1);
    __syncthreads();                       // buf[u&1] ready
    const char* buf = (const char*)Bs + (u&1)*16384;
    int kh = u&1;
    int hsel = (u>=8)? ((u>>1)&1) : (u>>2);
    __builtin_amdgcn_s_setprio(1);
    if(u<8){
      int m = (u>>1)&1;
      const u8* Ab = (m==0? A1 : A2) + (size_t)(m0+lr)*256;
      #pragma unroll
      for(int kq=0;kq<4;++kq){
        int k0 = kh*128 + kq*32;
        long bx = *(const long*)(Ab + k0 + lk8);
        #pragma unroll
        for(int nt=0;nt<8;++nt){
          unsigned row = nt*16+lr;
          unsigned byte = (row*128u + kq*32 + lk8) ^ ((row&15u)<<3);
          long a = *(const long*)(buf + byte);
          acc[hsel*8+nt] = __builtin_amdgcn_mfma_f32_16x16x32_fp8_fp8(a,bx,acc[hsel*8+nt],0,0,0);
        }
      }
    } else {
      #pragma unroll
      for(int kq=0;kq<4;++kq){
        int k0 = kh*128 + kq*32;
        unsigned ab = (((unsigned)lr<<8) + k0 + lk8) ^ ((lr&15u)<<3);
        long bx = *(const long*)(xlw + ab);
        #pragma unroll
        for(int nt=0;nt<8;++nt){
          unsigned row = nt*16+lr;
          unsigned byte = (row*128u + kq*32 + lk8) ^ ((row&15u)<<3);
          long a = *(const long*)(buf + byte);
          acc[hsel*8+nt] = __builtin_amdgcn_mfma_f32_16x16x32_fp8_fp8(a,bx,acc[hsel*8+nt],0,0,0);
        }
      }
    }
    __builtin_amdgcn_s_setprio(0);
    if(u<11) commit((u&1)^1);
    if(u==3){
      #pragma unroll
      for(int nt=0;nt<8;++nt){
        f32x4 v = acc[nt];
        unsigned pk = __builtin_amdgcn_cvt_pk_fp8_f32(silu_f(v[0]), silu_f(v[1]), 0, false);
        pk = __builtin_amdgcn_cvt_pk_fp8_f32(silu_f(v[2]), silu_f(v[3]), pk, true);
        unsigned byte = (((unsigned)lr<<8) + nt*16 + lkgrp*4) ^ ((lr&15u)<<3);
        *(unsigned*)(xlw + byte) = pk;
      }
    }
    if(u==7){
      #pragma unroll
      for(int nt=0;nt<8;++nt){
        f32x4 v = acc[8+nt];
        unsigned pk = __builtin_amdgcn_cvt_pk_fp8_f32(silu_f(v[0]), silu_f(v[1]), 0, false);
        pk = __builtin_amdgcn_cvt_pk_fp8_f32(silu_f(v[2]), silu_f(v[3]), pk, true);
        unsigned byte = (((unsigned)lr<<8) + 128 + nt*16 + lkgrp*4) ^ ((lr&15u)<<3);
        *(unsigned*)(xlw + byte) = pk;
      }
      #pragma unroll
      for(int i=0;i<16;i++) acc[i]=(f32x4){0.f,0.f,0.f,0.f};
    }
  }

  // epilogue: h1 = silu(acc + bd1) -> Bs (dword, swizzled) -> coalesced 8B copy
  __syncthreads();
  #pragma unroll
  for(int h=0;h<2;++h){
    #pragma unroll
    for(int nt=0;nt<8;++nt){
      f32x4 v = acc[h*8+nt];
      int F = h*128 + nt*16 + lkgrp*4;
      unsigned pk = __builtin_amdgcn_cvt_pk_fp8_f32(silu_f(v[0]+bd1[F+0]), silu_f(v[1]+bd1[F+1]), 0, false);
      pk = __builtin_amdgcn_cvt_pk_fp8_f32(silu_f(v[2]+bd1[F+2]), silu_f(v[3]+bd1[F+3]), pk, true);
      unsigned row = (unsigned)(wave*16 + lr);
      unsigned byte = ((row<<8) + (unsigned)F) ^ ((row&15u)<<3);
      *(unsigned*)((char*)Bs + byte) = pk;
    }
  }
  __syncthreads();
  #pragma unroll
  for(int it=0; it<8; ++it){
    unsigned byte = (unsigned)(it*512 + t)*8;
    unsigned src = byte ^ (((byte>>8)&15u)<<3);
    long v = *(const long*)((const char*)Bs + src);
    *(long*)(outb + (size_t)blockIdx.x*32768 + byte) = v;
  }
}

// ---------------- per-graph seg-sum of h1 (fp8 in, bf16 out), 4 graphs/block ----------------
__global__ void k_sg8(const u8* __restrict__ h18, const int* __restrict__ gstart,
                      u16* __restrict__ sgb){
  int lane = threadIdx.x&63;
  int g = blockIdx.x*4 + (threadIdx.x>>6);
  int s0=gstart[g], s1=gstart[g+1];
  float a0=0.f,a1=0.f,a2=0.f,a3=0.f;
  for(int i=s0;i<s1;i++){
    unsigned w = *(const unsigned*)(h18 + (size_t)i*256 + lane*4);
    float4 v = e4m3x4(w);
    a0+=v.x; a1+=v.y; a2+=v.z; a3+=v.w;
  }
  us4 o; o.x=f2bf(a0); o.y=f2bf(a1); o.z=f2bf(a2); o.w=f2bf(a3);
  *(us4*)(sgb + (size_t)g*256 + lane*4) = o;
}

// ---------------- fused head: xg -> h -> logits+CE -> (last block) final ----------------
__global__ __launch_bounds__(256) void k_head3(const u16* __restrict__ sgb,
        const int* __restrict__ gstart, const float* __restrict__ bd2,
        const u16* __restrict__ wd2b, const u16* __restrict__ wpeb,
        const float* __restrict__ bp1, const u16* __restrict__ wp2b,
        const float* __restrict__ bp2, const int* __restrict__ nlv,
        float* __restrict__ accum, int* __restrict__ done,
        float* __restrict__ out){
  __shared__ u16 S[64*256];
  int t = threadIdx.x;
  int wave = t>>6, lane = t&63;
  int lr = lane&15, lkgrp = lane>>4, lk = lkgrp*8;
  int g0 = blockIdx.x*64;
  int rw = wave*16;

  f32x4 acc[16];
  #pragma unroll
  for(int nt=0;nt<16;nt++) acc[nt]=(f32x4){0.f,0.f,0.f,0.f};
  #pragma unroll
  for(int k0=0;k0<256;k0+=32){
    short8 a = *(const short8*)(sgb + (size_t)(g0+rw+lr)*256 + k0 + lk);
    #pragma unroll
    for(int nt=0;nt<16;nt++){
      short8 b = *(const short8*)(wd2b + (size_t)(nt*16+lr)*256 + k0 + lk);
      acc[nt] = __builtin_amdgcn_mfma_f32_16x16x32_bf16(a,b,acc[nt],0,0,0);
    }
  }
  #pragma unroll
  for(int j=0;j<4;j++){
    unsigned gl = rw + lkgrp*4 + j;
    float cnt = (float)(gstart[g0+gl+1]-gstart[g0+gl]);
    #pragma unroll
    for(int nt=0;nt<16;nt++){
      int c = nt*16+lr;
      float v = acc[nt][j] + cnt*bd2[c];
      *(u16*)((char*)S + ((((gl<<9) + c*2)) ^ ((gl&7u)<<4))) = f2bf(v);
    }
  }

  #pragma unroll
  for(int nt=0;nt<16;nt++) acc[nt]=(f32x4){0.f,0.f,0.f,0.f};
  #pragma unroll
  for(int k0=0;k0<256;k0+=32){
    unsigned row = rw+lr;
    short8 a = *(const short8*)((char*)S + (((row<<9) + (k0+lk)*2) ^ ((row&7u)<<4)));
    #pragma unroll
    for(int nt=0;nt<16;nt++){
      short8 b = *(const short8*)(wpeb + (size_t)(nt*16+lr)*256 + k0 + lk);
      acc[nt] = __builtin_amdgcn_mfma_f32_16x16x32_bf16(a,b,acc[nt],0,0,0);
    }
  }
  #pragma unroll
  for(int j=0;j<4;j++){
    unsigned gl = rw + lkgrp*4 + j;
    #pragma unroll
    for(int nt=0;nt<16;nt++){
      int c = nt*16+lr;
      float v = silu_f(acc[nt][j] + bp1[c]);
      *(u16*)((char*)S + ((((gl<<9) + c*2)) ^ ((gl&7u)<<4))) = f2bf(v);
    }
  }

  #pragma unroll
  for(int nt=0;nt<4;nt++) acc[nt]=(f32x4){0.f,0.f,0.f,0.f};
  #pragma unroll
  for(int k0=0;k0<256;k0+=32){
    unsigned row = rw+lr;
    short8 a = *(const short8*)((char*)S + (((row<<9) + (k0+lk)*2) ^ ((row&7u)<<4)));
    #pragma unroll
    for(int nt=0;nt<4;nt++){
      short8 b = *(const short8*)(wp2b + (size_t)(nt*16+lr)*256 + k0 + lk);
      acc[nt] = __builtin_amdgcn_mfma_f32_16x16x32_bf16(a,b,acc[nt],0,0,0);
    }
  }
  float bp[4];
  #pragma unroll
  for(int nt=0;nt<4;nt++){
    int c = nt*16+lr;
    bp[nt] = (c<NL)? bp2[c] : 0.f;
  }
  float s = 0.f;
  #pragma unroll
  for(int j=0;j<4;j++){
    int g = g0 + rw + lkgrp*4 + j;
    int tgt = nlv[g];
    float mx = -1e30f, pk = 0.f;
    float lg[4];
    #pragma unroll
    for(int nt=0;nt<4;nt++){
      int c = nt*16+lr;
      lg[nt] = (c<NL)? (acc[nt][j] + bp[nt]) : -1e30f;
      mx = fmaxf(mx, lg[nt]);
      if(c==tgt) pk = lg[nt];
    }
    #pragma unroll
    for(int o=1;o<16;o<<=1) mx = fmaxf(mx, __shfl_xor(mx,o));
    float se = 0.f;
    #pragma unroll
    for(int nt=0;nt<4;nt++) se += __expf(lg[nt]-mx);
    #pragma unroll
    for(int o=1;o<16;o<<=1) se += __shfl_xor(se,o);
    #pragma unroll
    for(int o=1;o<16;o<<=1) pk += __shfl_xor(pk,o);
    s += logf(se)+mx - pk;
  }
  if(lr==0) atomicAdd(&accum[1], s);
  __syncthreads();
  if(t==0){
    __threadfence();
    int old = atomicAdd(done, 1);
    if(old == 31){                          // last of 32 blocks
      float l0 = atomicAdd(&accum[0], 0.0f);
      float l1 = atomicAdd(&accum[1], 0.0f);
      out[0] = l0/(float)NG;
      out[1] = l1/(float)NG;
    }
  }
}

// ---------------- launcher ----------------
extern "C" void kernel_launch(void* const* d_in, const int* in_sizes, int n_in,
                              void* d_out, int out_size, void* d_ws, size_t ws_size,
                              hipStream_t stream){
  (void)in_sizes; (void)n_in; (void)out_size; (void)ws_size;
  const float* x      = (const float*)d_in[0];
  const float* pos    = (const float*)d_in[1];
  const float* noise  = (const float*)d_in[2];
  const int*   n2g    = (const int*)d_in[3];
  const int*   ei     = (const int*)d_in[4];
  const int*   nl     = (const int*)d_in[5];
  const float* W_node = (const float*)d_in[6];
  const float* W_msg  = (const float*)d_in[7];
  const float* w_gate = (const float*)d_in[8];
  const float* Wd1    = (const float*)d_in[9];
  const float* bd1    = (const float*)d_in[10];
  const float* Wd2    = (const float*)d_in[11];
  const float* bd2    = (const float*)d_in[12];
  const float* Wp1    = (const float*)d_in[17];
  const float* bp1    = (const float*)d_in[18];
  const float* Wp2    = (const float*)d_in[19];
  const float* bp2    = (const float*)d_in[20];
  float* out = (float*)d_out;

  char* w = (char*)d_ws;
  size_t off = 0;
  auto alloc = [&](size_t bytes)->void*{
    void* p = w + off;
    off += (bytes + 255) & ~(size_t)255;
    return p;
  };

  // --- zeroed region ---
  size_t zstart = off;
  int*   cnt_e   = (int*)alloc((size_t)NN*4);
  float* accum   = (float*)alloc(2*4);
  int*   done    = (int*)alloc(4);
  size_t zend = off;

  // --- other buffers ---
  u8*   xb8  = (u8*)alloc((size_t)NN*HD);
  u8*   xs8  = (u8*)alloc((size_t)NN*HD);
  u8*   h18  = (u8*)alloc((size_t)NN*HD);
  u16*  sgb  = (u16*)alloc((size_t)NG*HD*2);
  float* sigg   = (float*)alloc((size_t)NG*4);
  float* posp   = (float*)alloc((size_t)NN*3*4);
  float* target = (float*)alloc((size_t)NN*3*4);
  float* cf     = (float*)alloc((size_t)NN*4);
  int*  gstart  = (int*)alloc((size_t)(NG+1)*4);
  u16*  elist   = (u16*)alloc((size_t)NN*CAP*2);   // 8MB bucket CSR (u16 ids)
  u8*   wn8     = (u8*)alloc((size_t)HD*HD);
  u8*   wm8     = (u8*)alloc((size_t)HD*HD);
  u8*   wd18    = (u8*)alloc((size_t)HD*HD);
  u16*  wd2b    = (u16*)alloc((size_t)HD*HD*2);
  u16*  wpeb    = (u16*)alloc((size_t)HD*HD*2);
  u16*  wp2b    = (u16*)alloc((size_t)64*HD*2);
  float* wmg    = (float*)alloc((size_t)HD*4);

  (void)hipMemsetAsync(w+zstart, 0, zend-zstart, stream);

  // pre: wmg | graph boundaries
  k_pre   <<<258,256,0,stream>>>(W_msg,w_gate,n2g,wmg,gstart);

  // front3: wall | prep8 | count-scatter | kab
  k_front3<<<12096,256,0,stream>>>(x,ei,W_node,W_msg,Wd1,Wd2,Wp1,Wp2,
                                   pos,noise,gstart,nl,wmg,
                                   wn8,wm8,wd18,wd2b,wpeb,wp2b,
                                   xb8,cf,cnt_e,elist,sigg,posp,target);

  // gather | eloss
  k_ge    <<<16640,256,0,stream>>>(xb8,cnt_e,elist,xs8,
                                   posp,cf,target,sigg,n2g,accum);

  // GNN node chain
  gemmF8  <<<512,512,0,stream>>>(xb8,xs8,wn8,wm8,wd18,bd1,h18);

  // graph rep + head (ce, fused final)
  k_sg8   <<<512,256,0,stream>>>(h18,gstart,sgb);
  k_head3 <<<NG/64,256,0,stream>>>(sgb,gstart,bd2,wd2b,wpeb,bp1,wp2b,bp2,nl,
                                   accum,done,out);
}

// Round 17
// 214.220 us; speedup vs baseline: 2.0705x; 1.0621x over previous
//
#include <hip/hip_runtime.h>
#include <math.h>

#define NN 65536   // nodes
#define NE 524288  // edges
#define NG 2048    // graphs
#define HD 256     // hidden
#define NL 50      // noise levels
#define CAP 64     // bucket capacity per node (Poisson(8): P(deg>64) ~ 1e-38)

typedef unsigned short u16;
typedef unsigned char u8;
typedef __attribute__((ext_vector_type(8))) short short8;
typedef __attribute__((ext_vector_type(4))) float f32x4;
typedef __attribute__((ext_vector_type(4))) unsigned short us4;

__device__ __forceinline__ float bf2f(u16 h){
  union{unsigned int u; float f;} v; v.u = ((unsigned int)h)<<16; return v.f;
}
__device__ __forceinline__ u16 f2bf(float f){
  union{float f; unsigned int u;} v; v.f=f;
  return (u16)((v.u + 0x7FFFu + ((v.u>>16)&1u))>>16);
}
__device__ __forceinline__ float silu_f(float v){ return v/(1.0f+__expf(-v)); }
__device__ __forceinline__ u8 f2e4m3(float v){
  return (u8)__builtin_amdgcn_cvt_pk_fp8_f32(v, v, 0, false);
}
__device__ __forceinline__ float4 e4m3x4(unsigned w){
  float4 r;
  r.x = __builtin_amdgcn_cvt_f32_fp8(w, 0);
  r.y = __builtin_amdgcn_cvt_f32_fp8(w, 1);
  r.z = __builtin_amdgcn_cvt_f32_fp8(w, 2);
  r.w = __builtin_amdgcn_cvt_f32_fp8(w, 3);
  return r;
}

#define WRED(v) { v += __shfl_xor(v,1); v += __shfl_xor(v,2); v += __shfl_xor(v,4); \
                  v += __shfl_xor(v,8); v += __shfl_xor(v,16); v += __shfl_xor(v,32); }

// =========== k_pre: wmg (block 0) | graph boundaries (blocks 1..257) ===========
__global__ void k_pre(const float* __restrict__ Wm, const float* __restrict__ wgate,
                      const int* __restrict__ n2g,
                      float* __restrict__ wmg, int* __restrict__ gstart){
  int b = blockIdx.x, t = threadIdx.x;
  if(b==0){
    float s=0.f;
    for(int j=0;j<256;j++) s += Wm[t*256+j]*wgate[j];
    wmg[t]=s;
  } else {
    int i = (b-1)*256 + t;
    if(i>NN) return;
    int cur  = (i<NN)? n2g[i] : NG;
    int prev = (i==0)? -1 : n2g[i-1];
    for(int g=prev+1; g<=cur; ++g) gstart[g]=i;
  }
}

// =========== k_front3: scatter | kab | wall | prep8(4 rows/wave) ===========
// Latency-bound sections FIRST (dispatch order), BW-streaming prep8 LAST.
// blocks: [0,512) scatter (4 edges/thr) | [512,1024) kab (4 graphs/block) |
//         [1024,2368) wall | [2368,6464) prep8
__global__ __launch_bounds__(256) void k_front3(
        const float* __restrict__ x, const int* __restrict__ ei,
        const float* __restrict__ Wn, const float* __restrict__ Wm,
        const float* __restrict__ Wd1, const float* __restrict__ Wd2,
        const float* __restrict__ Wp1, const float* __restrict__ Wp2,
        const float* __restrict__ pos, const float* __restrict__ noise,
        const int* __restrict__ gstart, const int* __restrict__ nl,
        const float* __restrict__ wmg,
        u8* __restrict__ wn8, u8* __restrict__ wm8, u8* __restrict__ wd18,
        u16* __restrict__ wd2b, u16* __restrict__ wpeb, u16* __restrict__ wp2b,
        u8* __restrict__ xb8, float* __restrict__ cf,
        int* __restrict__ cnt_e, u16* __restrict__ elist,
        float* __restrict__ sigg, float* __restrict__ posp,
        float* __restrict__ target){
  int b = blockIdx.x, t = threadIdx.x;
  if(b < 512){
    // scatter: 4 edges per thread (int4 loads)
    int e0 = (b*256 + t)*4;
    int4 s4 = *(const int4*)(ei + e0);
    int4 d4 = *(const int4*)(ei + NE + e0);
    #pragma unroll
    for(int q=0;q<4;++q){
      int src = (q==0)? s4.x : (q==1)? s4.y : (q==2)? s4.z : s4.w;
      int dst = (q==0)? d4.x : (q==1)? d4.y : (q==2)? d4.z : d4.w;
      int slot = atomicAdd(&cnt_e[dst],1);
      if(slot<CAP) elist[(size_t)dst*CAP+slot] = (u16)src;
    }
    return;
  }
  if(b < 1024){
    // ---- kab: 4 graphs per block ----
    int bb2 = b - 512;
    int wid = (bb2<<2) + (t>>6);
    int lane = t & 63;
    int s0 = gstart[wid], s1 = gstart[wid+1];
    const double L0 =  2.3025850929940456840;  // ln 10
    const double L1 = -4.6051701859880913680;  // ln 0.01
    float sg = (float)exp(L0 + (double)nl[wid]*(L1-L0)/49.0);
    if(lane==0) sigg[wid]=sg;

    float sx=0,sy=0,sz=0, tx=0,ty=0,tz=0;
    for(int i=s0+lane;i<s1;i+=64){
      float px=pos[3*i],py=pos[3*i+1],pz=pos[3*i+2];
      sx+=px; sy+=py; sz+=pz;
      tx+=px+noise[3*i]*sg; ty+=py+noise[3*i+1]*sg; tz+=pz+noise[3*i+2]*sg;
    }
    WRED(sx); WRED(sy); WRED(sz); WRED(tx); WRED(ty); WRED(tz);
    float invc = 1.f/fmaxf((float)(s1-s0),1.f);
    float cx=sx*invc, cy=sy*invc, cz=sz*invc;
    float pcx=tx*invc, pcy=ty*invc, pcz=tz*invc;

    float h00=0,h01=0,h02=0,h10=0,h11=0,h12=0,h20=0,h21=0,h22=0;
    for(int i=s0+lane;i<s1;i+=64){
      float px=pos[3*i],py=pos[3*i+1],pz=pos[3*i+2];
      float a0=px+noise[3*i]*sg-pcx, a1=py+noise[3*i+1]*sg-pcy, a2=pz+noise[3*i+2]*sg-pcz;
      float b0=px-cx, b1=py-cy, b2=pz-cz;
      h00+=a0*b0; h01+=a0*b1; h02+=a0*b2;
      h10+=a1*b0; h11+=a1*b1; h12+=a1*b2;
      h20+=a2*b0; h21+=a2*b1; h22+=a2*b2;
    }
    WRED(h00); WRED(h01); WRED(h02); WRED(h10); WRED(h11); WRED(h12);
    WRED(h20); WRED(h21); WRED(h22);

    float X[3][3] = {{h00,h10,h20},{h01,h11,h21},{h02,h12,h22}};
    float nf=0.f;
    #pragma unroll
    for(int r=0;r<3;r++) for(int c=0;c<3;c++) nf += X[r][c]*X[r][c];
    nf = sqrtf(nf);
    if(nf < 1e-20f){
      #pragma unroll
      for(int r=0;r<3;r++) for(int c=0;c<3;c++) X[r][c]=(r==c)?1.f:0.f;
    } else {
      float s0f=1.f/nf;
      #pragma unroll
      for(int r=0;r<3;r++) for(int c=0;c<3;c++) X[r][c]*=s0f;
      for(int it=0; it<30; ++it){
        float a=X[0][0],bq=X[0][1],c=X[0][2];
        float d=X[1][0],e=X[1][1],f=X[1][2];
        float gg=X[2][0],h=X[2][1],ii=X[2][2];
        float A_= e*ii-f*h, B_=-(d*ii-f*gg), C_= d*h-e*gg;
        float D_=-(bq*ii-c*h), E_= a*ii-c*gg, F_=-(a*h-bq*gg);
        float G_= bq*f-c*e,  H_=-(a*f-c*d),  I_= a*e-bq*d;
        float det = a*A_ + bq*B_ + c*C_;
        if(!(fabsf(det) > 1e-25f)){
          if(it==0){
            for(int r=0;r<3;r++) for(int cc=0;cc<3;cc++) X[r][cc]=(r==cc)?1.f:0.f;
          }
          break;
        }
        float si = 0.5f/det;
        float Y00=0.5f*a + si*A_, Y01=0.5f*bq + si*B_, Y02=0.5f*c + si*C_;
        float Y10=0.5f*d + si*D_, Y11=0.5f*e + si*E_, Y12=0.5f*f + si*F_;
        float Y20=0.5f*gg+ si*G_, Y21=0.5f*h + si*H_, Y22=0.5f*ii+ si*I_;
        X[0][0]=Y00; X[0][1]=Y01; X[0][2]=Y02;
        X[1][0]=Y10; X[1][1]=Y11; X[1][2]=Y12;
        X[2][0]=Y20; X[2][1]=Y21; X[2][2]=Y22;
      }
    }
    float T0 = cx - (X[0][0]*pcx + X[0][1]*pcy + X[0][2]*pcz);
    float T1 = cy - (X[1][0]*pcx + X[1][1]*pcy + X[1][2]*pcz);
    float T2 = cz - (X[2][0]*pcx + X[2][1]*pcy + X[2][2]*pcz);
    float is = 1.f/sg;
    for(int i=s0+lane;i<s1;i+=64){
      float px=pos[3*i],py=pos[3*i+1],pz=pos[3*i+2];
      float qx=px+noise[3*i]*sg, qy=py+noise[3*i+1]*sg, qz=pz+noise[3*i+2]*sg;
      float ox = X[0][0]*qx + X[0][1]*qy + X[0][2]*qz + T0;
      float oy = X[1][0]*qx + X[1][1]*qy + X[1][2]*qz + T1;
      float oz = X[2][0]*qx + X[2][1]*qy + X[2][2]*qz + T2;
      posp[3*i]=ox; posp[3*i+1]=oy; posp[3*i+2]=oz;
      target[3*i]=(px-ox)*is; target[3*i+1]=(py-oy)*is; target[3*i+2]=(pz-oz)*is;
    }
    return;
  }
  if(b < 2368){
    int bb = b - 1024;
    if(bb < 768){
      int m = bb>>8;
      int idx = (bb&255)*256 + t;
      int k = idx>>8, n = idx&255;
      const float* W = (m==0)? Wn : (m==1)? Wm : Wd1;
      u8* O = (m==0)? wn8 : (m==1)? wm8 : wd18;
      unsigned a = (unsigned)(n*256+k);
      O[a ^ ((unsigned)(n&15)<<3)] = f2e4m3(W[k*256+n]);   // pre-swizzled
    } else if(bb < 1024){
      int idx = (bb-768)*256 + t; int k=idx>>8, n=idx&255;
      wd2b[n*256+k] = f2bf(Wd2[k*256+n]);
    } else if(bb < 1280){
      int idx = (bb-1024)*256 + t; int k=idx>>8, n=idx&255;
      wpeb[n*256+k] = f2bf(Wp1[k*256+n] + Wp1[(k+256)*256+n]);
    } else {
      int idx = (bb-1280)*256 + t; int k=idx&255, n=idx>>8;
      wp2b[n*256+k] = (n<NL)? f2bf(Wp2[k*NL+n]) : (u16)0;
    }
    return;
  }
  // ---- prep8: 4 rows per wave (ILP 4) ----
  {
    int wave = t>>6, lane = t&63;
    int i0 = (((b-2368)*4 + wave)<<2);
    float4 a0 = ((const float4*)(x + (size_t)(i0+0)*256))[lane];
    float4 a1 = ((const float4*)(x + (size_t)(i0+1)*256))[lane];
    float4 a2 = ((const float4*)(x + (size_t)(i0+2)*256))[lane];
    float4 a3 = ((const float4*)(x + (size_t)(i0+3)*256))[lane];
    float4 bb = ((const float4*)wmg)[lane];
    float s0 = a0.x*bb.x + a0.y*bb.y + a0.z*bb.z + a0.w*bb.w;
    float s1 = a1.x*bb.x + a1.y*bb.y + a1.z*bb.z + a1.w*bb.w;
    float s2 = a2.x*bb.x + a2.y*bb.y + a2.z*bb.z + a2.w*bb.w;
    float s3 = a3.x*bb.x + a3.y*bb.y + a3.z*bb.z + a3.w*bb.w;
    unsigned w0 = __builtin_amdgcn_cvt_pk_fp8_f32(a0.x, a0.y, 0, false);
    w0 = __builtin_amdgcn_cvt_pk_fp8_f32(a0.z, a0.w, w0, true);
    unsigned w1 = __builtin_amdgcn_cvt_pk_fp8_f32(a1.x, a1.y, 0, false);
    w1 = __builtin_amdgcn_cvt_pk_fp8_f32(a1.z, a1.w, w1, true);
    unsigned w2 = __builtin_amdgcn_cvt_pk_fp8_f32(a2.x, a2.y, 0, false);
    w2 = __builtin_amdgcn_cvt_pk_fp8_f32(a2.z, a2.w, w2, true);
    unsigned w3 = __builtin_amdgcn_cvt_pk_fp8_f32(a3.x, a3.y, 0, false);
    w3 = __builtin_amdgcn_cvt_pk_fp8_f32(a3.z, a3.w, w3, true);
    *(unsigned*)(xb8 + (size_t)(i0+0)*256 + lane*4) = w0;
    *(unsigned*)(xb8 + (size_t)(i0+1)*256 + lane*4) = w1;
    *(unsigned*)(xb8 + (size_t)(i0+2)*256 + lane*4) = w2;
    *(unsigned*)(xb8 + (size_t)(i0+3)*256 + lane*4) = w3;
    #pragma unroll
    for(int o=32;o;o>>=1){
      s0 += __shfl_down(s0,o); s1 += __shfl_down(s1,o);
      s2 += __shfl_down(s2,o); s3 += __shfl_down(s3,o);
    }
    if(lane==0){
      cf[i0+0]=silu_f(s0); cf[i0+1]=silu_f(s1);
      cf[i0+2]=silu_f(s2); cf[i0+3]=silu_f(s3);
    }
  }
}

// =========== k_ge: gather (bucket CSR, u16) | eloss ===========
// blocks: [0,16384) gather, 4 nodes/block | [16384,16640) eloss
__global__ void k_ge(const u8* __restrict__ xb8, const int* __restrict__ cnt_e,
                     const u16* __restrict__ elist, u8* __restrict__ xs8,
                     const float* __restrict__ posp, const float* __restrict__ cf,
                     const float* __restrict__ target, const float* __restrict__ sigg,
                     const int* __restrict__ n2g, float* __restrict__ accum){
  int b = blockIdx.x, t = threadIdx.x;
  if(b < 16384){
    int lane = t & 63;
    int c = b*4 + (t>>6);
    int deg = min(cnt_e[c], CAP);
    const u16* el = elist + (size_t)c*CAP;
    float a0=0.f,a1=0.f,a2=0.f,a3=0.f;
    int e=0;
    for(; e+3<deg; e+=4){
      int r0=el[e], r1=el[e+1], r2=el[e+2], r3=el[e+3];
      unsigned w0 = *(const unsigned*)(xb8 + (size_t)r0*256 + lane*4);
      unsigned w1 = *(const unsigned*)(xb8 + (size_t)r1*256 + lane*4);
      unsigned w2 = *(const unsigned*)(xb8 + (size_t)r2*256 + lane*4);
      unsigned w3 = *(const unsigned*)(xb8 + (size_t)r3*256 + lane*4);
      float4 v0 = e4m3x4(w0), v1 = e4m3x4(w1), v2 = e4m3x4(w2), v3 = e4m3x4(w3);
      a0 += (v0.x+v1.x)+(v2.x+v3.x); a1 += (v0.y+v1.y)+(v2.y+v3.y);
      a2 += (v0.z+v1.z)+(v2.z+v3.z); a3 += (v0.w+v1.w)+(v2.w+v3.w);
    }
    for(; e<deg; ++e){
      unsigned w0 = *(const unsigned*)(xb8 + (size_t)el[e]*256 + lane*4);
      float4 v0 = e4m3x4(w0);
      a0+=v0.x; a1+=v0.y; a2+=v0.z; a3+=v0.w;
    }
    unsigned w = __builtin_amdgcn_cvt_pk_fp8_f32(a0, a1, 0, false);
    w = __builtin_amdgcn_cvt_pk_fp8_f32(a2, a3, w, true);
    *(unsigned*)(xs8 + (size_t)c*256 + lane*4) = w;
  } else {
    int i = (b-16384)*256 + t;
    float s=0.f;
    {
      int deg = min(cnt_e[i], CAP);
      const u16* el = elist + (size_t)i*CAP;
      float px=posp[i*3+0], py=posp[i*3+1], pz=posp[i*3+2];
      float dx=0.f, dy=0.f, dz=0.f;
      for(int e=0;e<deg;e++){
        int r=el[e];
        float c=cf[r];
        dx += (posp[r*3+0]-px)*c;
        dy += (posp[r*3+1]-py)*c;
        dz += (posp[r*3+2]-pz)*c;
      }
      float is = 1.f/sigg[n2g[i]];
      float d0 = dx*is - target[i*3+0];
      float d1 = dy*is - target[i*3+1];
      float d2 = dz*is - target[i*3+2];
      s = d0*d0+d1*d1+d2*d2;
    }
    #pragma unroll
    for(int o=32;o;o>>=1) s += __shfl_down(s,o);
    if((t&63)==0) atomicAdd(&accum[0], s);
  }
}

// ---------------- fused fp8 node GEMM chain (r12 + T5 setprio) ----------------
__global__ __launch_bounds__(512) void gemmF8(
    const u8* __restrict__ A1, const u8* __restrict__ A2,
    const u8* __restrict__ Wn, const u8* __restrict__ Wm,
    const u8* __restrict__ Wd, const float* __restrict__ bd1,
    u8* __restrict__ outb){
  __shared__ u8 Bs[32768];   // 2x16KB ping-pong; whole 32KB reused by epilogue
  __shared__ u8 XL[32768];   // per-wave xl (4KB each)
  int t = threadIdx.x;
  int wave = t>>6, lane = t&63;
  int lr = lane&15, lkgrp = lane>>4, lk8 = lkgrp*8;
  int m0 = blockIdx.x*128 + wave*16;
  char* xlw = (char*)XL + wave*4096;
  int row_t = t>>2, col_t = (t&3)*32;   // staging: 32B per thread

  f32x4 acc[16];
  #pragma unroll
  for(int i=0;i<16;i++) acc[i]=(f32x4){0.f,0.f,0.f,0.f};

  short8 pre0, pre1;
  auto preload = [&](int u){
    const u8* W = (u>=8)? Wd : (((u>>1)&1)? Wm : Wn);
    int h  = (u>=8)? ((u>>1)&1) : (u>>2);
    int kh = u&1;
    const u8* s = W + (size_t)(h*128 + row_t)*256 + kh*128 + col_t;
    pre0 = *(const short8*)(s);
    pre1 = *(const short8*)(s+16);
  };
  auto commit = [&](int p){
    char* d = (char*)Bs + p*16384 + row_t*128 + col_t;
    *(short8*)(d)    = pre0;
    *(short8*)(d+16) = pre1;
  };

  preload(0); commit(0);
  #pragma unroll
  for(int u=0; u<12; ++u){
    if(u<11) preload(u+1);
    __syncthreads();                       // buf[u&1] ready
    const char* buf = (const char*)Bs + (u&1)*16384;
    int kh = u&1;
    int hsel = (u>=8)? ((u>>1)&1) : (u>>2);
    __builtin_amdgcn_s_setprio(1);
    if(u<8){
      int m = (u>>1)&1;
      const u8* Ab = (m==0? A1 : A2) + (size_t)(m0+lr)*256;
      #pragma unroll
      for(int kq=0;kq<4;++kq){
        int k0 = kh*128 + kq*32;
        long bx = *(const long*)(Ab + k0 + lk8);
        #pragma unroll
        for(int nt=0;nt<8;++nt){
          unsigned row = nt*16+lr;
          unsigned byte = (row*128u + kq*32 + lk8) ^ ((row&15u)<<3);
          long a = *(const long*)(buf + byte);
          acc[hsel*8+nt] = __builtin_amdgcn_mfma_f32_16x16x32_fp8_fp8(a,bx,acc[hsel*8+nt],0,0,0);
        }
      }
    } else {
      #pragma unroll
      for(int kq=0;kq<4;++kq){
        int k0 = kh*128 + kq*32;
        unsigned ab = (((unsigned)lr<<8) + k0 + lk8) ^ ((lr&15u)<<3);
        long bx = *(const long*)(xlw + ab);
        #pragma unroll
        for(int nt=0;nt<8;++nt){
          unsigned row = nt*16+lr;
          unsigned byte = (row*128u + kq*32 + lk8) ^ ((row&15u)<<3);
          long a = *(const long*)(buf + byte);
          acc[hsel*8+nt] = __builtin_amdgcn_mfma_f32_16x16x32_fp8_fp8(a,bx,acc[hsel*8+nt],0,0,0);
        }
      }
    }
    __builtin_amdgcn_s_setprio(0);
    if(u<11) commit((u&1)^1);
    if(u==3){
      #pragma unroll
      for(int nt=0;nt<8;++nt){
        f32x4 v = acc[nt];
        unsigned pk = __builtin_amdgcn_cvt_pk_fp8_f32(silu_f(v[0]), silu_f(v[1]), 0, false);
        pk = __builtin_amdgcn_cvt_pk_fp8_f32(silu_f(v[2]), silu_f(v[3]), pk, true);
        unsigned byte = (((unsigned)lr<<8) + nt*16 + lkgrp*4) ^ ((lr&15u)<<3);
        *(unsigned*)(xlw + byte) = pk;
      }
    }
    if(u==7){
      #pragma unroll
      for(int nt=0;nt<8;++nt){
        f32x4 v = acc[8+nt];
        unsigned pk = __builtin_amdgcn_cvt_pk_fp8_f32(silu_f(v[0]), silu_f(v[1]), 0, false);
        pk = __builtin_amdgcn_cvt_pk_fp8_f32(silu_f(v[2]), silu_f(v[3]), pk, true);
        unsigned byte = (((unsigned)lr<<8) + 128 + nt*16 + lkgrp*4) ^ ((lr&15u)<<3);
        *(unsigned*)(xlw + byte) = pk;
      }
      #pragma unroll
      for(int i=0;i<16;i++) acc[i]=(f32x4){0.f,0.f,0.f,0.f};
    }
  }

  // epilogue: h1 = silu(acc + bd1) -> Bs (dword, swizzled) -> coalesced 8B copy
  __syncthreads();
  #pragma unroll
  for(int h=0;h<2;++h){
    #pragma unroll
    for(int nt=0;nt<8;++nt){
      f32x4 v = acc[h*8+nt];
      int F = h*128 + nt*16 + lkgrp*4;
      unsigned pk = __builtin_amdgcn_cvt_pk_fp8_f32(silu_f(v[0]+bd1[F+0]), silu_f(v[1]+bd1[F+1]), 0, false);
      pk = __builtin_amdgcn_cvt_pk_fp8_f32(silu_f(v[2]+bd1[F+2]), silu_f(v[3]+bd1[F+3]), pk, true);
      unsigned row = (unsigned)(wave*16 + lr);
      unsigned byte = ((row<<8) + (unsigned)F) ^ ((row&15u)<<3);
      *(unsigned*)((char*)Bs + byte) = pk;
    }
  }
  __syncthreads();
  #pragma unroll
  for(int it=0; it<8; ++it){
    unsigned byte = (unsigned)(it*512 + t)*8;
    unsigned src = byte ^ (((byte>>8)&15u)<<3);
    long v = *(const long*)((const char*)Bs + src);
    *(long*)(outb + (size_t)blockIdx.x*32768 + byte) = v;
  }
}

// ---------------- per-graph seg-sum of h1 (fp8 in, bf16 out), 4 graphs/block ----------------
__global__ void k_sg8(const u8* __restrict__ h18, const int* __restrict__ gstart,
                      u16* __restrict__ sgb){
  int lane = threadIdx.x&63;
  int g = blockIdx.x*4 + (threadIdx.x>>6);
  int s0=gstart[g], s1=gstart[g+1];
  float a0=0.f,a1=0.f,a2=0.f,a3=0.f;
  for(int i=s0;i<s1;i++){
    unsigned w = *(const unsigned*)(h18 + (size_t)i*256 + lane*4);
    float4 v = e4m3x4(w);
    a0+=v.x; a1+=v.y; a2+=v.z; a3+=v.w;
  }
  us4 o; o.x=f2bf(a0); o.y=f2bf(a1); o.z=f2bf(a2); o.w=f2bf(a3);
  *(us4*)(sgb + (size_t)g*256 + lane*4) = o;
}

// ---------------- fused head: xg -> h -> logits+CE -> (last block) final ----------------
__global__ __launch_bounds__(256) void k_head3(const u16* __restrict__ sgb,
        const int* __restrict__ gstart, const float* __restrict__ bd2,
        const u16* __restrict__ wd2b, const u16* __restrict__ wpeb,
        const float* __restrict__ bp1, const u16* __restrict__ wp2b,
        const float* __restrict__ bp2, const int* __restrict__ nlv,
        float* __restrict__ accum, int* __restrict__ done,
        float* __restrict__ out){
  __shared__ u16 S[64*256];
  int t = threadIdx.x;
  int wave = t>>6, lane = t&63;
  int lr = lane&15, lkgrp = lane>>4, lk = lkgrp*8;
  int g0 = blockIdx.x*64;
  int rw = wave*16;

  f32x4 acc[16];
  #pragma unroll
  for(int nt=0;nt<16;nt++) acc[nt]=(f32x4){0.f,0.f,0.f,0.f};
  #pragma unroll
  for(int k0=0;k0<256;k0+=32){
    short8 a = *(const short8*)(sgb + (size_t)(g0+rw+lr)*256 + k0 + lk);
    #pragma unroll
    for(int nt=0;nt<16;nt++){
      short8 b = *(const short8*)(wd2b + (size_t)(nt*16+lr)*256 + k0 + lk);
      acc[nt] = __builtin_amdgcn_mfma_f32_16x16x32_bf16(a,b,acc[nt],0,0,0);
    }
  }
  #pragma unroll
  for(int j=0;j<4;j++){
    unsigned gl = rw + lkgrp*4 + j;
    float cnt = (float)(gstart[g0+gl+1]-gstart[g0+gl]);
    #pragma unroll
    for(int nt=0;nt<16;nt++){
      int c = nt*16+lr;
      float v = acc[nt][j] + cnt*bd2[c];
      *(u16*)((char*)S + ((((gl<<9) + c*2)) ^ ((gl&7u)<<4))) = f2bf(v);
    }
  }

  #pragma unroll
  for(int nt=0;nt<16;nt++) acc[nt]=(f32x4){0.f,0.f,0.f,0.f};
  #pragma unroll
  for(int k0=0;k0<256;k0+=32){
    unsigned row = rw+lr;
    short8 a = *(const short8*)((char*)S + (((row<<9) + (k0+lk)*2) ^ ((row&7u)<<4)));
    #pragma unroll
    for(int nt=0;nt<16;nt++){
      short8 b = *(const short8*)(wpeb + (size_t)(nt*16+lr)*256 + k0 + lk);
      acc[nt] = __builtin_amdgcn_mfma_f32_16x16x32_bf16(a,b,acc[nt],0,0,0);
    }
  }
  #pragma unroll
  for(int j=0;j<4;j++){
    unsigned gl = rw + lkgrp*4 + j;
    #pragma unroll
    for(int nt=0;nt<16;nt++){
      int c = nt*16+lr;
      float v = silu_f(acc[nt][j] + bp1[c]);
      *(u16*)((char*)S + ((((gl<<9) + c*2)) ^ ((gl&7u)<<4))) = f2bf(v);
    }
  }

  #pragma unroll
  for(int nt=0;nt<4;nt++) acc[nt]=(f32x4){0.f,0.f,0.f,0.f};
  #pragma unroll
  for(int k0=0;k0<256;k0+=32){
    unsigned row = rw+lr;
    short8 a = *(const short8*)((char*)S + (((row<<9) + (k0+lk)*2) ^ ((row&7u)<<4)));
    #pragma unroll
    for(int nt=0;nt<4;nt++){
      short8 b = *(const short8*)(wp2b + (size_t)(nt*16+lr)*256 + k0 + lk);
      acc[nt] = __builtin_amdgcn_mfma_f32_16x16x32_bf16(a,b,acc[nt],0,0,0);
    }
  }
  float bp[4];
  #pragma unroll
  for(int nt=0;nt<4;nt++){
    int c = nt*16+lr;
    bp[nt] = (c<NL)? bp2[c] : 0.f;
  }
  float s = 0.f;
  #pragma unroll
  for(int j=0;j<4;j++){
    int g = g0 + rw + lkgrp*4 + j;
    int tgt = nlv[g];
    float mx = -1e30f, pk = 0.f;
    float lg[4];
    #pragma unroll
    for(int nt=0;nt<4;nt++){
      int c = nt*16+lr;
      lg[nt] = (c<NL)? (acc[nt][j] + bp[nt]) : -1e30f;
      mx = fmaxf(mx, lg[nt]);
      if(c==tgt) pk = lg[nt];
    }
    #pragma unroll
    for(int o=1;o<16;o<<=1) mx = fmaxf(mx, __shfl_xor(mx,o));
    float se = 0.f;
    #pragma unroll
    for(int nt=0;nt<4;nt++) se += __expf(lg[nt]-mx);
    #pragma unroll
    for(int o=1;o<16;o<<=1) se += __shfl_xor(se,o);
    #pragma unroll
    for(int o=1;o<16;o<<=1) pk += __shfl_xor(pk,o);
    s += logf(se)+mx - pk;
  }
  if(lr==0) atomicAdd(&accum[1], s);
  __syncthreads();
  if(t==0){
    __threadfence();
    int old = atomicAdd(done, 1);
    if(old == 31){                          // last of 32 blocks
      float l0 = atomicAdd(&accum[0], 0.0f);
      float l1 = atomicAdd(&accum[1], 0.0f);
      out[0] = l0/(float)NG;
      out[1] = l1/(float)NG;
    }
  }
}

// ---------------- launcher ----------------
extern "C" void kernel_launch(void* const* d_in, const int* in_sizes, int n_in,
                              void* d_out, int out_size, void* d_ws, size_t ws_size,
                              hipStream_t stream){
  (void)in_sizes; (void)n_in; (void)out_size; (void)ws_size;
  const float* x      = (const float*)d_in[0];
  const float* pos    = (const float*)d_in[1];
  const float* noise  = (const float*)d_in[2];
  const int*   n2g    = (const int*)d_in[3];
  const int*   ei     = (const int*)d_in[4];
  const int*   nl     = (const int*)d_in[5];
  const float* W_node = (const float*)d_in[6];
  const float* W_msg  = (const float*)d_in[7];
  const float* w_gate = (const float*)d_in[8];
  const float* Wd1    = (const float*)d_in[9];
  const float* bd1    = (const float*)d_in[10];
  const float* Wd2    = (const float*)d_in[11];
  const float* bd2    = (const float*)d_in[12];
  const float* Wp1    = (const float*)d_in[17];
  const float* bp1    = (const float*)d_in[18];
  const float* Wp2    = (const float*)d_in[19];
  const float* bp2    = (const float*)d_in[20];
  float* out = (float*)d_out;

  char* w = (char*)d_ws;
  size_t off = 0;
  auto alloc = [&](size_t bytes)->void*{
    void* p = w + off;
    off += (bytes + 255) & ~(size_t)255;
    return p;
  };

  // --- zeroed region ---
  size_t zstart = off;
  int*   cnt_e   = (int*)alloc((size_t)NN*4);
  float* accum   = (float*)alloc(2*4);
  int*   done    = (int*)alloc(4);
  size_t zend = off;

  // --- other buffers ---
  u8*   xb8  = (u8*)alloc((size_t)NN*HD);
  u8*   xs8  = (u8*)alloc((size_t)NN*HD);
  u8*   h18  = (u8*)alloc((size_t)NN*HD);
  u16*  sgb  = (u16*)alloc((size_t)NG*HD*2);
  float* sigg   = (float*)alloc((size_t)NG*4);
  float* posp   = (float*)alloc((size_t)NN*3*4);
  float* target = (float*)alloc((size_t)NN*3*4);
  float* cf     = (float*)alloc((size_t)NN*4);
  int*  gstart  = (int*)alloc((size_t)(NG+1)*4);
  u16*  elist   = (u16*)alloc((size_t)NN*CAP*2);   // 8MB bucket CSR (u16 ids)
  u8*   wn8     = (u8*)alloc((size_t)HD*HD);
  u8*   wm8     = (u8*)alloc((size_t)HD*HD);
  u8*   wd18    = (u8*)alloc((size_t)HD*HD);
  u16*  wd2b    = (u16*)alloc((size_t)HD*HD*2);
  u16*  wpeb    = (u16*)alloc((size_t)HD*HD*2);
  u16*  wp2b    = (u16*)alloc((size_t)64*HD*2);
  float* wmg    = (float*)alloc((size_t)HD*4);

  (void)hipMemsetAsync(w+zstart, 0, zend-zstart, stream);

  // pre: wmg | graph boundaries
  k_pre   <<<258,256,0,stream>>>(W_msg,w_gate,n2g,wmg,gstart);

  // front3: scatter | kab | wall | prep8
  k_front3<<<6464,256,0,stream>>>(x,ei,W_node,W_msg,Wd1,Wd2,Wp1,Wp2,
                                  pos,noise,gstart,nl,wmg,
                                  wn8,wm8,wd18,wd2b,wpeb,wp2b,
                                  xb8,cf,cnt_e,elist,sigg,posp,target);

  // gather | eloss
  k_ge    <<<16640,256,0,stream>>>(xb8,cnt_e,elist,xs8,
                                   posp,cf,target,sigg,n2g,accum);

  // GNN node chain
  gemmF8  <<<512,512,0,stream>>>(xb8,xs8,wn8,wm8,wd18,bd1,h18);

  // graph rep + head (ce, fused final)
  k_sg8   <<<512,256,0,stream>>>(h18,gstart,sgb);
  k_head3 <<<NG/64,256,0,stream>>>(sgb,gstart,bd2,wd2b,wpeb,bp1,wp2b,bp2,nl,
                                   accum,done,out);
}

// Round 18
// 211.961 us; speedup vs baseline: 2.0926x; 1.0107x over previous
//
#include <hip/hip_runtime.h>
#include <math.h>

#define NN 65536   // nodes
#define NE 524288  // edges
#define NG 2048    // graphs
#define HD 256     // hidden
#define NL 50      // noise levels
#define CAP 32     // bucket capacity = one 64B sector (Poisson(8): P(deg>32) ~ 2e-11)

typedef unsigned short u16;
typedef unsigned char u8;
typedef __attribute__((ext_vector_type(8))) short short8;
typedef __attribute__((ext_vector_type(4))) float f32x4;
typedef __attribute__((ext_vector_type(4))) unsigned short us4;

__device__ __forceinline__ float bf2f(u16 h){
  union{unsigned int u; float f;} v; v.u = ((unsigned int)h)<<16; return v.f;
}
__device__ __forceinline__ u16 f2bf(float f){
  union{float f; unsigned int u;} v; v.f=f;
  return (u16)((v.u + 0x7FFFu + ((v.u>>16)&1u))>>16);
}
__device__ __forceinline__ float silu_f(float v){ return v/(1.0f+__expf(-v)); }
__device__ __forceinline__ u8 f2e4m3(float v){
  return (u8)__builtin_amdgcn_cvt_pk_fp8_f32(v, v, 0, false);
}
__device__ __forceinline__ float4 e4m3x4(unsigned w){
  float4 r;
  r.x = __builtin_amdgcn_cvt_f32_fp8(w, 0);
  r.y = __builtin_amdgcn_cvt_f32_fp8(w, 1);
  r.z = __builtin_amdgcn_cvt_f32_fp8(w, 2);
  r.w = __builtin_amdgcn_cvt_f32_fp8(w, 3);
  return r;
}

#define WRED(v) { v += __shfl_xor(v,1); v += __shfl_xor(v,2); v += __shfl_xor(v,4); \
                  v += __shfl_xor(v,8); v += __shfl_xor(v,16); v += __shfl_xor(v,32); }

// =========== k_pre: wmg (block 0) | graph boundaries (blocks 1..257) ===========
__global__ void k_pre(const float* __restrict__ Wm, const float* __restrict__ wgate,
                      const int* __restrict__ n2g,
                      float* __restrict__ wmg, int* __restrict__ gstart){
  int b = blockIdx.x, t = threadIdx.x;
  if(b==0){
    float s=0.f;
    for(int j=0;j<256;j++) s += Wm[t*256+j]*wgate[j];
    wmg[t]=s;
  } else {
    int i = (b-1)*256 + t;
    if(i>NN) return;
    int cur  = (i<NN)? n2g[i] : NG;
    int prev = (i==0)? -1 : n2g[i-1];
    for(int g=prev+1; g<=cur; ++g) gstart[g]=i;
  }
}

// =========== k_front3: scatter | kab | wall | prep8(4 rows/wave) ===========
// blocks: [0,512) scatter (4 edges/thr) | [512,1024) kab (4 graphs/block) |
//         [1024,2368) wall | [2368,6464) prep8
__global__ __launch_bounds__(256) void k_front3(
        const float* __restrict__ x, const int* __restrict__ ei,
        const float* __restrict__ Wn, const float* __restrict__ Wm,
        const float* __restrict__ Wd1, const float* __restrict__ Wd2,
        const float* __restrict__ Wp1, const float* __restrict__ Wp2,
        const float* __restrict__ pos, const float* __restrict__ noise,
        const int* __restrict__ gstart, const int* __restrict__ nl,
        const float* __restrict__ wmg,
        u8* __restrict__ wn8, u8* __restrict__ wm8, u8* __restrict__ wd18,
        u16* __restrict__ wd2b, u16* __restrict__ wpeb, u16* __restrict__ wp2b,
        u8* __restrict__ xb8, float* __restrict__ cf,
        int* __restrict__ cnt_e, u16* __restrict__ elist,
        float* __restrict__ sigg, float* __restrict__ posp,
        float* __restrict__ target){
  int b = blockIdx.x, t = threadIdx.x;
  if(b < 512){
    // scatter: 4 edges per thread (int4 loads); elist row = one 64B sector
    int e0 = (b*256 + t)*4;
    int4 s4 = *(const int4*)(ei + e0);
    int4 d4 = *(const int4*)(ei + NE + e0);
    #pragma unroll
    for(int q=0;q<4;++q){
      int src = (q==0)? s4.x : (q==1)? s4.y : (q==2)? s4.z : s4.w;
      int dst = (q==0)? d4.x : (q==1)? d4.y : (q==2)? d4.z : d4.w;
      int slot = atomicAdd(&cnt_e[dst],1);
      if(slot<CAP) elist[(size_t)dst*CAP+slot] = (u16)src;
    }
    return;
  }
  if(b < 1024){
    // ---- kab: 4 graphs per block ----
    int bb2 = b - 512;
    int wid = (bb2<<2) + (t>>6);
    int lane = t & 63;
    int s0 = gstart[wid], s1 = gstart[wid+1];
    const double L0 =  2.3025850929940456840;  // ln 10
    const double L1 = -4.6051701859880913680;  // ln 0.01
    float sg = (float)exp(L0 + (double)nl[wid]*(L1-L0)/49.0);
    if(lane==0) sigg[wid]=sg;

    float sx=0,sy=0,sz=0, tx=0,ty=0,tz=0;
    for(int i=s0+lane;i<s1;i+=64){
      float px=pos[3*i],py=pos[3*i+1],pz=pos[3*i+2];
      sx+=px; sy+=py; sz+=pz;
      tx+=px+noise[3*i]*sg; ty+=py+noise[3*i+1]*sg; tz+=pz+noise[3*i+2]*sg;
    }
    WRED(sx); WRED(sy); WRED(sz); WRED(tx); WRED(ty); WRED(tz);
    float invc = 1.f/fmaxf((float)(s1-s0),1.f);
    float cx=sx*invc, cy=sy*invc, cz=sz*invc;
    float pcx=tx*invc, pcy=ty*invc, pcz=tz*invc;

    float h00=0,h01=0,h02=0,h10=0,h11=0,h12=0,h20=0,h21=0,h22=0;
    for(int i=s0+lane;i<s1;i+=64){
      float px=pos[3*i],py=pos[3*i+1],pz=pos[3*i+2];
      float a0=px+noise[3*i]*sg-pcx, a1=py+noise[3*i+1]*sg-pcy, a2=pz+noise[3*i+2]*sg-pcz;
      float b0=px-cx, b1=py-cy, b2=pz-cz;
      h00+=a0*b0; h01+=a0*b1; h02+=a0*b2;
      h10+=a1*b0; h11+=a1*b1; h12+=a1*b2;
      h20+=a2*b0; h21+=a2*b1; h22+=a2*b2;
    }
    WRED(h00); WRED(h01); WRED(h02); WRED(h10); WRED(h11); WRED(h12);
    WRED(h20); WRED(h21); WRED(h22);

    float X[3][3] = {{h00,h10,h20},{h01,h11,h21},{h02,h12,h22}};
    float nf=0.f;
    #pragma unroll
    for(int r=0;r<3;r++) for(int c=0;c<3;c++) nf += X[r][c]*X[r][c];
    nf = sqrtf(nf);
    if(nf < 1e-20f){
      #pragma unroll
      for(int r=0;r<3;r++) for(int c=0;c<3;c++) X[r][c]=(r==c)?1.f:0.f;
    } else {
      float s0f=1.f/nf;
      #pragma unroll
      for(int r=0;r<3;r++) for(int c=0;c<3;c++) X[r][c]*=s0f;
      for(int it=0; it<30; ++it){
        float a=X[0][0],bq=X[0][1],c=X[0][2];
        float d=X[1][0],e=X[1][1],f=X[1][2];
        float gg=X[2][0],h=X[2][1],ii=X[2][2];
        float A_= e*ii-f*h, B_=-(d*ii-f*gg), C_= d*h-e*gg;
        float D_=-(bq*ii-c*h), E_= a*ii-c*gg, F_=-(a*h-bq*gg);
        float G_= bq*f-c*e,  H_=-(a*f-c*d),  I_= a*e-bq*d;
        float det = a*A_ + bq*B_ + c*C_;
        if(!(fabsf(det) > 1e-25f)){
          if(it==0){
            for(int r=0;r<3;r++) for(int cc=0;cc<3;cc++) X[r][cc]=(r==cc)?1.f:0.f;
          }
          break;
        }
        float si = 0.5f/det;
        float Y00=0.5f*a + si*A_, Y01=0.5f*bq + si*B_, Y02=0.5f*c + si*C_;
        float Y10=0.5f*d + si*D_, Y11=0.5f*e + si*E_, Y12=0.5f*f + si*F_;
        float Y20=0.5f*gg+ si*G_, Y21=0.5f*h + si*H_, Y22=0.5f*ii+ si*I_;
        X[0][0]=Y00; X[0][1]=Y01; X[0][2]=Y02;
        X[1][0]=Y10; X[1][1]=Y11; X[1][2]=Y12;
        X[2][0]=Y20; X[2][1]=Y21; X[2][2]=Y22;
      }
    }
    float T0 = cx - (X[0][0]*pcx + X[0][1]*pcy + X[0][2]*pcz);
    float T1 = cy - (X[1][0]*pcx + X[1][1]*pcy + X[1][2]*pcz);
    float T2 = cz - (X[2][0]*pcx + X[2][1]*pcy + X[2][2]*pcz);
    float is = 1.f/sg;
    for(int i=s0+lane;i<s1;i+=64){
      float px=pos[3*i],py=pos[3*i+1],pz=pos[3*i+2];
      float qx=px+noise[3*i]*sg, qy=py+noise[3*i+1]*sg, qz=pz+noise[3*i+2]*sg;
      float ox = X[0][0]*qx + X[0][1]*qy + X[0][2]*qz + T0;
      float oy = X[1][0]*qx + X[1][1]*qy + X[1][2]*qz + T1;
      float oz = X[2][0]*qx + X[2][1]*qy + X[2][2]*qz + T2;
      posp[3*i]=ox; posp[3*i+1]=oy; posp[3*i+2]=oz;
      target[3*i]=(px-ox)*is; target[3*i+1]=(py-oy)*is; target[3*i+2]=(pz-oz)*is;
    }
    return;
  }
  if(b < 2368){
    int bb = b - 1024;
    if(bb < 768){
      int m = bb>>8;
      int idx = (bb&255)*256 + t;
      int k = idx>>8, n = idx&255;
      const float* W = (m==0)? Wn : (m==1)? Wm : Wd1;
      u8* O = (m==0)? wn8 : (m==1)? wm8 : wd18;
      unsigned a = (unsigned)(n*256+k);
      O[a ^ ((unsigned)(n&15)<<3)] = f2e4m3(W[k*256+n]);   // pre-swizzled
    } else if(bb < 1024){
      int idx = (bb-768)*256 + t; int k=idx>>8, n=idx&255;
      wd2b[n*256+k] = f2bf(Wd2[k*256+n]);
    } else if(bb < 1280){
      int idx = (bb-1024)*256 + t; int k=idx>>8, n=idx&255;
      wpeb[n*256+k] = f2bf(Wp1[k*256+n] + Wp1[(k+256)*256+n]);
    } else {
      int idx = (bb-1280)*256 + t; int k=idx&255, n=idx>>8;
      wp2b[n*256+k] = (n<NL)? f2bf(Wp2[k*NL+n]) : (u16)0;
    }
    return;
  }
  // ---- prep8: 4 rows per wave (ILP 4) ----
  {
    int wave = t>>6, lane = t&63;
    int i0 = (((b-2368)*4 + wave)<<2);
    float4 a0 = ((const float4*)(x + (size_t)(i0+0)*256))[lane];
    float4 a1 = ((const float4*)(x + (size_t)(i0+1)*256))[lane];
    float4 a2 = ((const float4*)(x + (size_t)(i0+2)*256))[lane];
    float4 a3 = ((const float4*)(x + (size_t)(i0+3)*256))[lane];
    float4 bb = ((const float4*)wmg)[lane];
    float s0 = a0.x*bb.x + a0.y*bb.y + a0.z*bb.z + a0.w*bb.w;
    float s1 = a1.x*bb.x + a1.y*bb.y + a1.z*bb.z + a1.w*bb.w;
    float s2 = a2.x*bb.x + a2.y*bb.y + a2.z*bb.z + a2.w*bb.w;
    float s3 = a3.x*bb.x + a3.y*bb.y + a3.z*bb.z + a3.w*bb.w;
    unsigned w0 = __builtin_amdgcn_cvt_pk_fp8_f32(a0.x, a0.y, 0, false);
    w0 = __builtin_amdgcn_cvt_pk_fp8_f32(a0.z, a0.w, w0, true);
    unsigned w1 = __builtin_amdgcn_cvt_pk_fp8_f32(a1.x, a1.y, 0, false);
    w1 = __builtin_amdgcn_cvt_pk_fp8_f32(a1.z, a1.w, w1, true);
    unsigned w2 = __builtin_amdgcn_cvt_pk_fp8_f32(a2.x, a2.y, 0, false);
    w2 = __builtin_amdgcn_cvt_pk_fp8_f32(a2.z, a2.w, w2, true);
    unsigned w3 = __builtin_amdgcn_cvt_pk_fp8_f32(a3.x, a3.y, 0, false);
    w3 = __builtin_amdgcn_cvt_pk_fp8_f32(a3.z, a3.w, w3, true);
    *(unsigned*)(xb8 + (size_t)(i0+0)*256 + lane*4) = w0;
    *(unsigned*)(xb8 + (size_t)(i0+1)*256 + lane*4) = w1;
    *(unsigned*)(xb8 + (size_t)(i0+2)*256 + lane*4) = w2;
    *(unsigned*)(xb8 + (size_t)(i0+3)*256 + lane*4) = w3;
    #pragma unroll
    for(int o=32;o;o>>=1){
      s0 += __shfl_down(s0,o); s1 += __shfl_down(s1,o);
      s2 += __shfl_down(s2,o); s3 += __shfl_down(s3,o);
    }
    if(lane==0){
      cf[i0+0]=silu_f(s0); cf[i0+1]=silu_f(s1);
      cf[i0+2]=silu_f(s2); cf[i0+3]=silu_f(s3);
    }
  }
}

// =========== k_ge: gather (bucket CSR, u16) | eloss ===========
// blocks: [0,16384) gather, 4 nodes/block | [16384,16640) eloss
__global__ void k_ge(const u8* __restrict__ xb8, const int* __restrict__ cnt_e,
                     const u16* __restrict__ elist, u8* __restrict__ xs8,
                     const float* __restrict__ posp, const float* __restrict__ cf,
                     const float* __restrict__ target, const float* __restrict__ sigg,
                     const int* __restrict__ n2g, float* __restrict__ accum){
  int b = blockIdx.x, t = threadIdx.x;
  if(b < 16384){
    int lane = t & 63;
    int c = b*4 + (t>>6);
    int deg = min(cnt_e[c], CAP);
    const u16* el = elist + (size_t)c*CAP;
    float a0=0.f,a1=0.f,a2=0.f,a3=0.f;
    int e=0;
    for(; e+3<deg; e+=4){
      int r0=el[e], r1=el[e+1], r2=el[e+2], r3=el[e+3];
      unsigned w0 = *(const unsigned*)(xb8 + (size_t)r0*256 + lane*4);
      unsigned w1 = *(const unsigned*)(xb8 + (size_t)r1*256 + lane*4);
      unsigned w2 = *(const unsigned*)(xb8 + (size_t)r2*256 + lane*4);
      unsigned w3 = *(const unsigned*)(xb8 + (size_t)r3*256 + lane*4);
      float4 v0 = e4m3x4(w0), v1 = e4m3x4(w1), v2 = e4m3x4(w2), v3 = e4m3x4(w3);
      a0 += (v0.x+v1.x)+(v2.x+v3.x); a1 += (v0.y+v1.y)+(v2.y+v3.y);
      a2 += (v0.z+v1.z)+(v2.z+v3.z); a3 += (v0.w+v1.w)+(v2.w+v3.w);
    }
    for(; e<deg; ++e){
      unsigned w0 = *(const unsigned*)(xb8 + (size_t)el[e]*256 + lane*4);
      float4 v0 = e4m3x4(w0);
      a0+=v0.x; a1+=v0.y; a2+=v0.z; a3+=v0.w;
    }
    unsigned w = __builtin_amdgcn_cvt_pk_fp8_f32(a0, a1, 0, false);
    w = __builtin_amdgcn_cvt_pk_fp8_f32(a2, a3, w, true);
    *(unsigned*)(xs8 + (size_t)c*256 + lane*4) = w;
  } else {
    int i = (b-16384)*256 + t;
    float s=0.f;
    {
      int deg = min(cnt_e[i], CAP);
      const u16* el = elist + (size_t)i*CAP;
      float px=posp[i*3+0], py=posp[i*3+1], pz=posp[i*3+2];
      float dx=0.f, dy=0.f, dz=0.f;
      for(int e=0;e<deg;e++){
        int r=el[e];
        float c=cf[r];
        dx += (posp[r*3+0]-px)*c;
        dy += (posp[r*3+1]-py)*c;
        dz += (posp[r*3+2]-pz)*c;
      }
      float is = 1.f/sigg[n2g[i]];
      float d0 = dx*is - target[i*3+0];
      float d1 = dy*is - target[i*3+1];
      float d2 = dz*is - target[i*3+2];
      s = d0*d0+d1*d1+d2*d2;
    }
    #pragma unroll
    for(int o=32;o;o>>=1) s += __shfl_down(s,o);
    if((t&63)==0) atomicAdd(&accum[0], s);
  }
}

// ---------------- fused fp8 node GEMM chain (r12 + T5 setprio) ----------------
__global__ __launch_bounds__(512) void gemmF8(
    const u8* __restrict__ A1, const u8* __restrict__ A2,
    const u8* __restrict__ Wn, const u8* __restrict__ Wm,
    const u8* __restrict__ Wd, const float* __restrict__ bd1,
    u8* __restrict__ outb){
  __shared__ u8 Bs[32768];   // 2x16KB ping-pong; whole 32KB reused by epilogue
  __shared__ u8 XL[32768];   // per-wave xl (4KB each)
  int t = threadIdx.x;
  int wave = t>>6, lane = t&63;
  int lr = lane&15, lkgrp = lane>>4, lk8 = lkgrp*8;
  int m0 = blockIdx.x*128 + wave*16;
  char* xlw = (char*)XL + wave*4096;
  int row_t = t>>2, col_t = (t&3)*32;   // staging: 32B per thread

  f32x4 acc[16];
  #pragma unroll
  for(int i=0;i<16;i++) acc[i]=(f32x4){0.f,0.f,0.f,0.f};

  short8 pre0, pre1;
  auto preload = [&](int u){
    const u8* W = (u>=8)? Wd : (((u>>1)&1)? Wm : Wn);
    int h  = (u>=8)? ((u>>1)&1) : (u>>2);
    int kh = u&1;
    const u8* s = W + (size_t)(h*128 + row_t)*256 + kh*128 + col_t;
    pre0 = *(const short8*)(s);
    pre1 = *(const short8*)(s+16);
  };
  auto commit = [&](int p){
    char* d = (char*)Bs + p*16384 + row_t*128 + col_t;
    *(short8*)(d)    = pre0;
    *(short8*)(d+16) = pre1;
  };

  preload(0); commit(0);
  #pragma unroll
  for(int u=0; u<12; ++u){
    if(u<11) preload(u+1);
    __syncthreads();                       // buf[u&1] ready
    const char* buf = (const char*)Bs + (u&1)*16384;
    int kh = u&1;
    int hsel = (u>=8)? ((u>>1)&1) : (u>>2);
    __builtin_amdgcn_s_setprio(1);
    if(u<8){
      int m = (u>>1)&1;
      const u8* Ab = (m==0? A1 : A2) + (size_t)(m0+lr)*256;
      #pragma unroll
      for(int kq=0;kq<4;++kq){
        int k0 = kh*128 + kq*32;
        long bx = *(const long*)(Ab + k0 + lk8);
        #pragma unroll
        for(int nt=0;nt<8;++nt){
          unsigned row = nt*16+lr;
          unsigned byte = (row*128u + kq*32 + lk8) ^ ((row&15u)<<3);
          long a = *(const long*)(buf + byte);
          acc[hsel*8+nt] = __builtin_amdgcn_mfma_f32_16x16x32_fp8_fp8(a,bx,acc[hsel*8+nt],0,0,0);
        }
      }
    } else {
      #pragma unroll
      for(int kq=0;kq<4;++kq){
        int k0 = kh*128 + kq*32;
        unsigned ab = (((unsigned)lr<<8) + k0 + lk8) ^ ((lr&15u)<<3);
        long bx = *(const long*)(xlw + ab);
        #pragma unroll
        for(int nt=0;nt<8;++nt){
          unsigned row = nt*16+lr;
          unsigned byte = (row*128u + kq*32 + lk8) ^ ((row&15u)<<3);
          long a = *(const long*)(buf + byte);
          acc[hsel*8+nt] = __builtin_amdgcn_mfma_f32_16x16x32_fp8_fp8(a,bx,acc[hsel*8+nt],0,0,0);
        }
      }
    }
    __builtin_amdgcn_s_setprio(0);
    if(u<11) commit((u&1)^1);
    if(u==3){
      #pragma unroll
      for(int nt=0;nt<8;++nt){
        f32x4 v = acc[nt];
        unsigned pk = __builtin_amdgcn_cvt_pk_fp8_f32(silu_f(v[0]), silu_f(v[1]), 0, false);
        pk = __builtin_amdgcn_cvt_pk_fp8_f32(silu_f(v[2]), silu_f(v[3]), pk, true);
        unsigned byte = (((unsigned)lr<<8) + nt*16 + lkgrp*4) ^ ((lr&15u)<<3);
        *(unsigned*)(xlw + byte) = pk;
      }
    }
    if(u==7){
      #pragma unroll
      for(int nt=0;nt<8;++nt){
        f32x4 v = acc[8+nt];
        unsigned pk = __builtin_amdgcn_cvt_pk_fp8_f32(silu_f(v[0]), silu_f(v[1]), 0, false);
        pk = __builtin_amdgcn_cvt_pk_fp8_f32(silu_f(v[2]), silu_f(v[3]), pk, true);
        unsigned byte = (((unsigned)lr<<8) + 128 + nt*16 + lkgrp*4) ^ ((lr&15u)<<3);
        *(unsigned*)(xlw + byte) = pk;
      }
      #pragma unroll
      for(int i=0;i<16;i++) acc[i]=(f32x4){0.f,0.f,0.f,0.f};
    }
  }

  // epilogue: h1 = silu(acc + bd1) -> Bs (dword, swizzled) -> coalesced 8B copy
  __syncthreads();
  #pragma unroll
  for(int h=0;h<2;++h){
    #pragma unroll
    for(int nt=0;nt<8;++nt){
      f32x4 v = acc[h*8+nt];
      int F = h*128 + nt*16 + lkgrp*4;
      unsigned pk = __builtin_amdgcn_cvt_pk_fp8_f32(silu_f(v[0]+bd1[F+0]), silu_f(v[1]+bd1[F+1]), 0, false);
      pk = __builtin_amdgcn_cvt_pk_fp8_f32(silu_f(v[2]+bd1[F+2]), silu_f(v[3]+bd1[F+3]), pk, true);
      unsigned row = (unsigned)(wave*16 + lr);
      unsigned byte = ((row<<8) + (unsigned)F) ^ ((row&15u)<<3);
      *(unsigned*)((char*)Bs + byte) = pk;
    }
  }
  __syncthreads();
  #pragma unroll
  for(int it=0; it<8; ++it){
    unsigned byte = (unsigned)(it*512 + t)*8;
    unsigned src = byte ^ (((byte>>8)&15u)<<3);
    long v = *(const long*)((const char*)Bs + src);
    *(long*)(outb + (size_t)blockIdx.x*32768 + byte) = v;
  }
}

// ---------------- per-graph seg-sum of h1 (fp8 in, bf16 out), 4 graphs/block ----------------
__global__ void k_sg8(const u8* __restrict__ h18, const int* __restrict__ gstart,
                      u16* __restrict__ sgb){
  int lane = threadIdx.x&63;
  int g = blockIdx.x*4 + (threadIdx.x>>6);
  int s0=gstart[g], s1=gstart[g+1];
  float a0=0.f,a1=0.f,a2=0.f,a3=0.f;
  for(int i=s0;i<s1;i++){
    unsigned w = *(const unsigned*)(h18 + (size_t)i*256 + lane*4);
    float4 v = e4m3x4(w);
    a0+=v.x; a1+=v.y; a2+=v.z; a3+=v.w;
  }
  us4 o; o.x=f2bf(a0); o.y=f2bf(a1); o.z=f2bf(a2); o.w=f2bf(a3);
  *(us4*)(sgb + (size_t)g*256 + lane*4) = o;
}

// ---------------- fused head: xg -> h -> logits+CE -> (last block) final ----------------
__global__ __launch_bounds__(256) void k_head3(const u16* __restrict__ sgb,
        const int* __restrict__ gstart, const float* __restrict__ bd2,
        const u16* __restrict__ wd2b, const u16* __restrict__ wpeb,
        const float* __restrict__ bp1, const u16* __restrict__ wp2b,
        const float* __restrict__ bp2, const int* __restrict__ nlv,
        float* __restrict__ accum, int* __restrict__ done,
        float* __restrict__ out){
  __shared__ u16 S[64*256];
  int t = threadIdx.x;
  int wave = t>>6, lane = t&63;
  int lr = lane&15, lkgrp = lane>>4, lk = lkgrp*8;
  int g0 = blockIdx.x*64;
  int rw = wave*16;

  f32x4 acc[16];
  #pragma unroll
  for(int nt=0;nt<16;nt++) acc[nt]=(f32x4){0.f,0.f,0.f,0.f};
  #pragma unroll
  for(int k0=0;k0<256;k0+=32){
    short8 a = *(const short8*)(sgb + (size_t)(g0+rw+lr)*256 + k0 + lk);
    #pragma unroll
    for(int nt=0;nt<16;nt++){
      short8 b = *(const short8*)(wd2b + (size_t)(nt*16+lr)*256 + k0 + lk);
      acc[nt] = __builtin_amdgcn_mfma_f32_16x16x32_bf16(a,b,acc[nt],0,0,0);
    }
  }
  #pragma unroll
  for(int j=0;j<4;j++){
    unsigned gl = rw + lkgrp*4 + j;
    float cnt = (float)(gstart[g0+gl+1]-gstart[g0+gl]);
    #pragma unroll
    for(int nt=0;nt<16;nt++){
      int c = nt*16+lr;
      float v = acc[nt][j] + cnt*bd2[c];
      *(u16*)((char*)S + ((((gl<<9) + c*2)) ^ ((gl&7u)<<4))) = f2bf(v);
    }
  }

  #pragma unroll
  for(int nt=0;nt<16;nt++) acc[nt]=(f32x4){0.f,0.f,0.f,0.f};
  #pragma unroll
  for(int k0=0;k0<256;k0+=32){
    unsigned row = rw+lr;
    short8 a = *(const short8*)((char*)S + (((row<<9) + (k0+lk)*2) ^ ((row&7u)<<4)));
    #pragma unroll
    for(int nt=0;nt<16;nt++){
      short8 b = *(const short8*)(wpeb + (size_t)(nt*16+lr)*256 + k0 + lk);
      acc[nt] = __builtin_amdgcn_mfma_f32_16x16x32_bf16(a,b,acc[nt],0,0,0);
    }
  }
  #pragma unroll
  for(int j=0;j<4;j++){
    unsigned gl = rw + lkgrp*4 + j;
    #pragma unroll
    for(int nt=0;nt<16;nt++){
      int c = nt*16+lr;
      float v = silu_f(acc[nt][j] + bp1[c]);
      *(u16*)((char*)S + ((((gl<<9) + c*2)) ^ ((gl&7u)<<4))) = f2bf(v);
    }
  }

  #pragma unroll
  for(int nt=0;nt<4;nt++) acc[nt]=(f32x4){0.f,0.f,0.f,0.f};
  #pragma unroll
  for(int k0=0;k0<256;k0+=32){
    unsigned row = rw+lr;
    short8 a = *(const short8*)((char*)S + (((row<<9) + (k0+lk)*2) ^ ((row&7u)<<4)));
    #pragma unroll
    for(int nt=0;nt<4;nt++){
      short8 b = *(const short8*)(wp2b + (size_t)(nt*16+lr)*256 + k0 + lk);
      acc[nt] = __builtin_amdgcn_mfma_f32_16x16x32_bf16(a,b,acc[nt],0,0,0);
    }
  }
  float bp[4];
  #pragma unroll
  for(int nt=0;nt<4;nt++){
    int c = nt*16+lr;
    bp[nt] = (c<NL)? bp2[c] : 0.f;
  }
  float s = 0.f;
  #pragma unroll
  for(int j=0;j<4;j++){
    int g = g0 + rw + lkgrp*4 + j;
    int tgt = nlv[g];
    float mx = -1e30f, pk = 0.f;
    float lg[4];
    #pragma unroll
    for(int nt=0;nt<4;nt++){
      int c = nt*16+lr;
      lg[nt] = (c<NL)? (acc[nt][j] + bp[nt]) : -1e30f;
      mx = fmaxf(mx, lg[nt]);
      if(c==tgt) pk = lg[nt];
    }
    #pragma unroll
    for(int o=1;o<16;o<<=1) mx = fmaxf(mx, __shfl_xor(mx,o));
    float se = 0.f;
    #pragma unroll
    for(int nt=0;nt<4;nt++) se += __expf(lg[nt]-mx);
    #pragma unroll
    for(int o=1;o<16;o<<=1) se += __shfl_xor(se,o);
    #pragma unroll
    for(int o=1;o<16;o<<=1) pk += __shfl_xor(pk,o);
    s += logf(se)+mx - pk;
  }
  if(lr==0) atomicAdd(&accum[1], s);
  __syncthreads();
  if(t==0){
    __threadfence();
    int old = atomicAdd(done, 1);
    if(old == 31){                          // last of 32 blocks
      float l0 = atomicAdd(&accum[0], 0.0f);
      float l1 = atomicAdd(&accum[1], 0.0f);
      out[0] = l0/(float)NG;
      out[1] = l1/(float)NG;
    }
  }
}

// ---------------- launcher ----------------
extern "C" void kernel_launch(void* const* d_in, const int* in_sizes, int n_in,
                              void* d_out, int out_size, void* d_ws, size_t ws_size,
                              hipStream_t stream){
  (void)in_sizes; (void)n_in; (void)out_size; (void)ws_size;
  const float* x      = (const float*)d_in[0];
  const float* pos    = (const float*)d_in[1];
  const float* noise  = (const float*)d_in[2];
  const int*   n2g    = (const int*)d_in[3];
  const int*   ei     = (const int*)d_in[4];
  const int*   nl     = (const int*)d_in[5];
  const float* W_node = (const float*)d_in[6];
  const float* W_msg  = (const float*)d_in[7];
  const float* w_gate = (const float*)d_in[8];
  const float* Wd1    = (const float*)d_in[9];
  const float* bd1    = (const float*)d_in[10];
  const float* Wd2    = (const float*)d_in[11];
  const float* bd2    = (const float*)d_in[12];
  const float* Wp1    = (const float*)d_in[17];
  const float* bp1    = (const float*)d_in[18];
  const float* Wp2    = (const float*)d_in[19];
  const float* bp2    = (const float*)d_in[20];
  float* out = (float*)d_out;

  char* w = (char*)d_ws;
  size_t off = 0;
  auto alloc = [&](size_t bytes)->void*{
    void* p = w + off;
    off += (bytes + 255) & ~(size_t)255;
    return p;
  };

  // --- zeroed region ---
  size_t zstart = off;
  int*   cnt_e   = (int*)alloc((size_t)NN*4);
  float* accum   = (float*)alloc(2*4);
  int*   done    = (int*)alloc(4);
  size_t zend = off;

  // --- other buffers ---
  u8*   xb8  = (u8*)alloc((size_t)NN*HD);
  u8*   xs8  = (u8*)alloc((size_t)NN*HD);
  u8*   h18  = (u8*)alloc((size_t)NN*HD);
  u16*  sgb  = (u16*)alloc((size_t)NG*HD*2);
  float* sigg   = (float*)alloc((size_t)NG*4);
  float* posp   = (float*)alloc((size_t)NN*3*4);
  float* target = (float*)alloc((size_t)NN*3*4);
  float* cf     = (float*)alloc((size_t)NN*4);
  int*  gstart  = (int*)alloc((size_t)(NG+1)*4);
  u16*  elist   = (u16*)alloc((size_t)NN*CAP*2);   // 4MB bucket CSR (one sector/node)
  u8*   wn8     = (u8*)alloc((size_t)HD*HD);
  u8*   wm8     = (u8*)alloc((size_t)HD*HD);
  u8*   wd18    = (u8*)alloc((size_t)HD*HD);
  u16*  wd2b    = (u16*)alloc((size_t)HD*HD*2);
  u16*  wpeb    = (u16*)alloc((size_t)HD*HD*2);
  u16*  wp2b    = (u16*)alloc((size_t)64*HD*2);
  float* wmg    = (float*)alloc((size_t)HD*4);

  (void)hipMemsetAsync(w+zstart, 0, zend-zstart, stream);

  // pre: wmg | graph boundaries
  k_pre   <<<258,256,0,stream>>>(W_msg,w_gate,n2g,wmg,gstart);

  // front3: scatter | kab | wall | prep8
  k_front3<<<6464,256,0,stream>>>(x,ei,W_node,W_msg,Wd1,Wd2,Wp1,Wp2,
                                  pos,noise,gstart,nl,wmg,
                                  wn8,wm8,wd18,wd2b,wpeb,wp2b,
                                  xb8,cf,cnt_e,elist,sigg,posp,target);

  // gather | eloss
  k_ge    <<<16640,256,0,stream>>>(xb8,cnt_e,elist,xs8,
                                   posp,cf,target,sigg,n2g,accum);

  // GNN node chain
  gemmF8  <<<512,512,0,stream>>>(xb8,xs8,wn8,wm8,wd18,bd1,h18);

  // graph rep + head (ce, fused final)
  k_sg8   <<<512,256,0,stream>>>(h18,gstart,sgb);
  k_head3 <<<NG/64,256,0,stream>>>(sgb,gstart,bd2,wd2b,wpeb,bp1,wp2b,bp2,nl,
                                   accum,done,out);
}